// Round 14
// baseline (432.780 us; speedup 1.0000x reference)
//
#include <hip/hip_runtime.h>
#include <math.h>

#define DIM   512
#define NB    4
#define NS    8192
#define FFT_N 8192
#define FT    1024
#define MTOT  (NB*NS)

// padded LDS index map for FFT: +1 float2 per 8 -> spreads tail/stage banks
#define IDX(i) ((i) + ((i) >> 3))
#define XSZ   9216

typedef __attribute__((ext_vector_type(8))) short bf16x8;
typedef __attribute__((ext_vector_type(4))) short short4v;
typedef __attribute__((ext_vector_type(8))) short short8v;
typedef __attribute__((ext_vector_type(4))) float f32x4;

// ---------------------------------------------------------------- helpers
__device__ __forceinline__ float bf2f(unsigned short u) {
    union { unsigned int i; float f; } v; v.i = ((unsigned int)u) << 16; return v.f;
}
__device__ __forceinline__ unsigned short f2bf(float f) {
    union { float f; unsigned int i; } v; v.f = f;
    unsigned int r = v.i + 0x7fffu + ((v.i >> 16) & 1u);
    return (unsigned short)(r >> 16);
}
__device__ __forceinline__ float2 cmulf(float2 a, float2 b) {
    return make_float2(a.x*b.x - a.y*b.y, a.x*b.y + a.y*b.x);
}
__device__ __forceinline__ float2 cadd(float2 a, float2 b) { return make_float2(a.x+b.x, a.y+b.y); }
__device__ __forceinline__ float2 csub(float2 a, float2 b) { return make_float2(a.x-b.x, a.y-b.y); }
__device__ __forceinline__ float gelu_exact(float x) {
    return 0.5f * x * (1.0f + erff(x * 0.70710678118654752f));
}
__device__ __forceinline__ void gload16(const void* g, void* l) {
    __builtin_amdgcn_global_load_lds((const __attribute__((address_space(1))) void*)g,
                                     (__attribute__((address_space(3))) void*)l, 16, 0, 0);
}

// ---- mega prep: cast_x | castT(w_in) | castT(w_out) | filter MLP -> filtT
// grid: [0,8192) cast_x · [8192,8384) w_inT · [8384,8448) w_outT · [8448,8576) mlpT
__device__ __forceinline__ void castT_body(const float* __restrict__ in,
                                           unsigned short* __restrict__ outT,
                                           int R, int C, int bx, int by, int t,
                                           float tile[64][65]) {
    const int c0 = bx * 64, r0 = by * 64;
    const int rr = t >> 4, c4 = (t & 15) * 4;
    #pragma unroll
    for (int p = 0; p < 4; ++p) {
        const int r = rr + p*16;
        float4 v = *(const float4*)&in[(size_t)(r0 + r)*C + c0 + c4];
        tile[r][c4+0]=v.x; tile[r][c4+1]=v.y; tile[r][c4+2]=v.z; tile[r][c4+3]=v.w;
    }
    __syncthreads();
    const int cc = t >> 4, r4 = (t & 15) * 4;
    #pragma unroll
    for (int p = 0; p < 4; ++p) {
        const int c = cc + p*16;
        short4v o;
        o[0] = (short)f2bf(tile[r4+0][c]); o[1] = (short)f2bf(tile[r4+1][c]);
        o[2] = (short)f2bf(tile[r4+2][c]); o[3] = (short)f2bf(tile[r4+3][c]);
        *(short4v*)&outT[(size_t)(c0 + c)*R + r0 + r4] = o;
    }
}

__global__ void mega_prep_kernel(const float* __restrict__ x, unsigned short* __restrict__ xb,
                                 const float* __restrict__ w_in, unsigned short* __restrict__ w_inT,
                                 const float* __restrict__ w_out, unsigned short* __restrict__ w_outT,
                                 const float* __restrict__ w1, const float* __restrict__ b1,
                                 const float* __restrict__ w2, const float* __restrict__ b2,
                                 const float* __restrict__ w3, const float* __restrict__ b3,
                                 float* __restrict__ filtT) {
    __shared__ float tile[64][65];
    __shared__ float h1s[64][65];
    const int bid = blockIdx.x;
    const int t = threadIdx.x;
    if (bid < 8192) {
        const size_t i = ((size_t)bid * 256 + t) * 8;
        float4 a = *(const float4*)&x[i];
        float4 b = *(const float4*)&x[i+4];
        short8v o;
        o[0]=(short)f2bf(a.x); o[1]=(short)f2bf(a.y); o[2]=(short)f2bf(a.z); o[3]=(short)f2bf(a.w);
        o[4]=(short)f2bf(b.x); o[5]=(short)f2bf(b.y); o[6]=(short)f2bf(b.z); o[7]=(short)f2bf(b.w);
        *(short8v*)&xb[i] = o;
    } else if (bid < 8384) {
        const int li = bid - 8192;
        castT_body(w_in, w_inT, DIM, 1536, li % 24, li / 24, t, tile);
    } else if (bid < 8448) {
        const int li = bid - 8384;
        castT_body(w_out, w_outT, DIM, DIM, li % 8, li / 8, t, tile);
    } else {
        // filter MLP -> filtT (D,S) directly. Block owns 64 consecutive s.
        const int s0 = (bid - 8448) * 64;
        // phase 1: h1[s][h], s,h in [0,64)
        for (int i = t; i < 4096; i += 256) {
            const int s = i >> 6, h = i & 63;
            const float pos = (float)(s0 + s) / (float)(NS - 1);
            h1s[s][h] = gelu_exact(pos * w1[h] + b1[h]);
        }
        __syncthreads();
        // phase 2: h2[s][h] into tile
        for (int i = t; i < 4096; i += 256) {
            const int s = i >> 6, h = i & 63;
            float acc = b2[h];
            #pragma unroll 8
            for (int j = 0; j < 64; ++j) acc += h1s[s][j] * w2[j*64 + h];
            tile[s][h] = gelu_exact(acc);
        }
        __syncthreads();
        // phase 3: out[d][s] = b3[d] + sum_j h2[s][j]*w3[j][d], write transposed
        const int dl = t >> 2, sq = t & 3;     // thread: d-lane (0..63), s-quad (0..3)
        for (int d0 = 0; d0 < DIM; d0 += 64) {
            const int d = d0 + dl;
            const float b3d = b3[d];
            float o[16];
            #pragma unroll
            for (int ss = 0; ss < 16; ++ss) o[ss] = b3d;
            const int sb = sq * 16;
            for (int j = 0; j < 64; ++j) {
                const float wj = w3[j*DIM + d];
                #pragma unroll
                for (int ss = 0; ss < 16; ++ss) o[ss] += tile[sb + ss][j] * wj;
            }
            float4* dst = (float4*)&filtT[(size_t)d*NS + s0 + sb];
            #pragma unroll
            for (int p = 0; p < 4; ++p)
                dst[p] = make_float4(o[4*p], o[4*p+1], o[4*p+2], o[4*p+3]);
        }
    }
}

// ---------------------------------------------------------------- FFT pieces
template<int LOGQ>
__device__ __forceinline__ void dif4_stage(float2* X) {
    const int q = 1 << LOGQ;
    const float step = -6.28318530717958647692f / (float)(4*q);
    #pragma unroll
    for (int it = 0; it < (FFT_N/4)/FT; ++it) {
        const int idx = threadIdx.x + it*FT;
        const int g = idx >> LOGQ, k = idx & (q-1);
        const int base = (g << (LOGQ+2)) + k;
        const int i0 = IDX(base), i1 = IDX(base+q), i2 = IDX(base+2*q), i3 = IDX(base+3*q);
        float2 a=X[i0], b=X[i1], c=X[i2], d=X[i3];
        float2 t0=cadd(a,c), t1=csub(a,c), t2=cadd(b,d), t3=csub(b,d);
        float2 y0=cadd(t0,t2), y2=csub(t0,t2);
        float2 y1=make_float2(t1.x+t3.y, t1.y-t3.x);   // t1 - i*t3
        float2 y3=make_float2(t1.x-t3.y, t1.y+t3.x);   // t1 + i*t3
        float sv, cv; __sincosf(step*(float)k, &sv, &cv);
        float2 w1=make_float2(cv, sv);
        float2 w2=cmulf(w1, w1);
        float2 w3=cmulf(w2, w1);
        X[i0] = y0;
        X[i1] = cmulf(y1, w1);
        X[i2] = cmulf(y2, w2);
        X[i3] = cmulf(y3, w3);
    }
    __syncthreads();
}

template<int LOGQ>
__device__ __forceinline__ void dit4_stage_inv(float2* X) {
    const int q = 1 << LOGQ;
    const float step = 6.28318530717958647692f / (float)(4*q);
    #pragma unroll
    for (int it = 0; it < (FFT_N/4)/FT; ++it) {
        const int idx = threadIdx.x + it*FT;
        const int g = idx >> LOGQ, k = idx & (q-1);
        const int base = (g << (LOGQ+2)) + k;
        const int i0 = IDX(base), i1 = IDX(base+q), i2 = IDX(base+2*q), i3 = IDX(base+3*q);
        float sv, cv; __sincosf(step*(float)k, &sv, &cv);
        float2 w1=make_float2(cv, sv);
        float2 w2=cmulf(w1, w1);
        float2 w3=cmulf(w2, w1);
        float2 u0=X[i0];
        float2 u1=cmulf(X[i1], w1);
        float2 u2=cmulf(X[i2], w2);
        float2 u3=cmulf(X[i3], w3);
        float2 s02=cadd(u0,u2), d02=csub(u0,u2);
        float2 s13=cadd(u1,u3), d13=csub(u1,u3);
        X[i0] = cadd(s02, s13);
        X[i2] = csub(s02, s13);
        X[i1] = make_float2(d02.x - d13.y, d02.y + d13.x);   // d02 + i*d13
        X[i3] = make_float2(d02.x + d13.y, d02.y - d13.x);   // d02 - i*d13
    }
    __syncthreads();
}

__device__ __forceinline__ void reg_fwd(float2* E) {
    const float C = 0.70710678118654752f;
    {
        float2 t0=cadd(E[0],E[4]), t1=csub(E[0],E[4]);
        float2 t2=cadd(E[2],E[6]), t3=csub(E[2],E[6]);
        E[0]=cadd(t0,t2);
        E[4]=csub(t0,t2);
        E[2]=make_float2(t1.x+t3.y, t1.y-t3.x);
        E[6]=make_float2(t1.x-t3.y, t1.y+t3.x);
    }
    {
        float2 t0=cadd(E[1],E[5]), t1=csub(E[1],E[5]);
        float2 t2=cadd(E[3],E[7]), t3=csub(E[3],E[7]);
        float2 y0=cadd(t0,t2), y2=csub(t0,t2);
        float2 y1=make_float2(t1.x+t3.y, t1.y-t3.x);
        float2 y3=make_float2(t1.x-t3.y, t1.y+t3.x);
        E[1]=y0;
        E[3]=make_float2(C*(y1.x+y1.y),  C*(y1.y-y1.x));
        E[5]=make_float2(y2.y, -y2.x);
        E[7]=make_float2(C*(y3.y-y3.x), -C*(y3.x+y3.y));
    }
    #pragma unroll
    for (int j = 0; j < 8; j += 2) {
        float2 a=E[j], b=E[j+1];
        E[j]=cadd(a,b); E[j+1]=csub(a,b);
    }
}
__device__ __forceinline__ void reg_inv(float2* E) {
    const float C = 0.70710678118654752f;
    #pragma unroll
    for (int j = 0; j < 8; j += 2) {
        float2 a=E[j], b=E[j+1];
        E[j]=cadd(a,b); E[j+1]=csub(a,b);
    }
    {
        float2 u0=E[0], u1=E[2], u2=E[4], u3=E[6];
        float2 s02=cadd(u0,u2), d02=csub(u0,u2);
        float2 s13=cadd(u1,u3), d13=csub(u1,u3);
        E[0]=cadd(s02,s13);
        E[4]=csub(s02,s13);
        E[2]=make_float2(d02.x - d13.y, d02.y + d13.x);
        E[6]=make_float2(d02.x + d13.y, d02.y - d13.x);
    }
    {
        float2 z1=E[3], z2=E[5], z3=E[7];
        float2 u0=E[1];
        float2 u1=make_float2(C*(z1.x - z1.y), C*(z1.x + z1.y));
        float2 u2=make_float2(-z2.y, z2.x);
        float2 u3=make_float2(-C*(z3.x + z3.y), C*(z3.x - z3.y));
        float2 s02=cadd(u0,u2), d02=csub(u0,u2);
        float2 s13=cadd(u1,u3), d13=csub(u1,u3);
        E[1]=cadd(s02,s13);
        E[5]=csub(s02,s13);
        E[3]=make_float2(d02.x - d13.y, d02.y + d13.x);
        E[7]=make_float2(d02.x + d13.y, d02.y - d13.x);
    }
}

// thread t owns logical elems 8t..8t+7 == phys 9t..9t+7 (contiguous)
__device__ __forceinline__ void load8p(const float2* X, int t, float2* E) {
    const float2* b = X + 9*t;
    #pragma unroll
    for (int j = 0; j < 8; ++j) E[j] = b[j];
}
__device__ __forceinline__ void store8p(float2* X, int t, const float2* E) {
    float2* b = X + 9*t;
    #pragma unroll
    for (int j = 0; j < 8; ++j) b[j] = E[j];
}

// -------- merged 1024-thread dispatch: blocks [0,512) fft_filt, [512,4608) conv+T
__global__ __launch_bounds__(FT)
void filtconv_kernel(const float* __restrict__ filtT, float2* __restrict__ Fbr,
                     const unsigned short* __restrict__ u,
                     const float* __restrict__ conv_w, const float* __restrict__ conv_b,
                     unsigned short* __restrict__ uT) {
    __shared__ __align__(16) char fsm[XSZ * sizeof(float2)];   // 72 KB union
    const int bid = blockIdx.x;
    const int t = threadIdx.x;
    if (bid < 512) {
        float2* X = (float2*)fsm;
        const int dd = bid;
        const float* f = filtT + (size_t)dd * FFT_N;
        {
            float4 a = *(const float4*)(f + 8*t);
            float4 b = *(const float4*)(f + 8*t + 4);
            float2 E[8];
            E[0]=make_float2(a.x,0.f); E[1]=make_float2(a.y,0.f);
            E[2]=make_float2(a.z,0.f); E[3]=make_float2(a.w,0.f);
            E[4]=make_float2(b.x,0.f); E[5]=make_float2(b.y,0.f);
            E[6]=make_float2(b.z,0.f); E[7]=make_float2(b.w,0.f);
            store8p(X, t, E);
        }
        __syncthreads();
        dif4_stage<11>(X);
        dif4_stage<9>(X);
        dif4_stage<7>(X);
        dif4_stage<5>(X);
        dif4_stage<3>(X);
        {
            float2 E[8];
            load8p(X, t, E);
            reg_fwd(E);
            float2* o = Fbr + (size_t)dd*FFT_N + 8*t;
            #pragma unroll
            for (int j = 0; j < 8; ++j) o[j] = E[j];
        }
    } else {
        float (*tile)[65] = (float(*)[65])fsm;                 // [66][65] = 16.8 KB
        const int lb = bid - 512;
        const int dt = lb & 7, st = (lb >> 3) & 127, b = lb >> 10;
        const int d0 = dt*64, s0 = st*64;
        const int rr = t >> 4, c4 = (t & 15) * 4;
        for (int r = rr; r < 66; r += 64) {
            const int s = s0 + r - 1;
            float v0=0.f, v1=0.f, v2=0.f, v3=0.f;
            if (s >= 0 && s < NS) {
                short4v xv = *(const short4v*)&u[((size_t)(b*NS + s))*DIM + d0 + c4];
                v0=bf2f((unsigned short)xv[0]); v1=bf2f((unsigned short)xv[1]);
                v2=bf2f((unsigned short)xv[2]); v3=bf2f((unsigned short)xv[3]);
            }
            tile[r][c4]=v0; tile[r][c4+1]=v1; tile[r][c4+2]=v2; tile[r][c4+3]=v3;
        }
        __syncthreads();
        const int dc = t >> 4, s4 = (t & 15) * 4;
        const int d = d0 + dc;
        const float w0 = conv_w[d*3], w1 = conv_w[d*3+1], w2 = conv_w[d*3+2];
        const float cb = conv_b[d];
        short4v o;
        #pragma unroll
        for (int j = 0; j < 4; ++j) {
            const int sx = s4 + j;
            const float val = tile[sx][dc]*w0 + tile[sx+1][dc]*w1 + tile[sx+2][dc]*w2 + cb;
            o[j] = (short)f2bf(val);
        }
        *(short4v*)&uT[((size_t)(b*DIM + d))*FFT_N + s0 + s4] = o;
    }
}

// packed-pair circular conv, in-place bf16: rows (2p,d) and (2p+1,d) of uT
__global__ __launch_bounds__(FT)
void fft_conv_kernel(unsigned short* __restrict__ uT, const float2* __restrict__ Fbr) {
    __shared__ float2 X[XSZ];
    const int d = blockIdx.x & (DIM - 1);
    const int p = blockIdx.x >> 9;
    unsigned short* u1 = uT + (size_t)((2*p    )*DIM + d) * FFT_N;
    unsigned short* u2 = uT + (size_t)((2*p + 1)*DIM + d) * FFT_N;
    const int t = threadIdx.x;
    {
        short8v a = *(const short8v*)(u1 + 8*t);
        short8v b = *(const short8v*)(u2 + 8*t);
        float2 E[8];
        #pragma unroll
        for (int j = 0; j < 8; ++j)
            E[j] = make_float2(bf2f((unsigned short)a[j]), bf2f((unsigned short)b[j]));
        store8p(X, t, E);
    }
    __syncthreads();
    dif4_stage<11>(X);
    dif4_stage<9>(X);
    dif4_stage<7>(X);
    dif4_stage<5>(X);
    dif4_stage<3>(X);
    {
        float2 E[8];
        load8p(X, t, E);
        reg_fwd(E);
        const float2* F = Fbr + (size_t)d*FFT_N + 8*t;
        #pragma unroll
        for (int j = 0; j < 8; ++j) E[j] = cmulf(E[j], F[j]);
        reg_inv(E);
        store8p(X, t, E);
    }
    __syncthreads();
    dit4_stage_inv<3>(X);
    dit4_stage_inv<5>(X);
    dit4_stage_inv<7>(X);
    dit4_stage_inv<9>(X);
    dit4_stage_inv<11>(X);
    {
        float2 E[8];
        load8p(X, t, E);
        const float sc = 1.0f / (float)FFT_N;
        short8v a, b;
        #pragma unroll
        for (int j = 0; j < 8; ++j) {
            a[j] = (short)f2bf(E[j].x * sc);
            b[j] = (short)f2bf(E[j].y * sc);
        }
        *(short8v*)(u1 + 8*t) = a;
        *(short8v*)(u2 + 8*t) = b;
    }
}

// ---------------------------------------------------------------- gating
__global__ void gate_kernel(unsigned short* __restrict__ vg, const unsigned short* __restrict__ yT) {
    __shared__ float tile[64][65];
    const int bid = blockIdx.x;
    const int dt = bid & 7, st = (bid >> 3) & 127, b = bid >> 10;
    const int d0 = dt*64, s0 = st*64;
    const int t = threadIdx.x;
    const int dl = t >> 4, s4 = (t & 15) * 4;
    #pragma unroll
    for (int p = 0; p < 4; ++p) {
        const int d = dl + p*16;
        short4v y = *(const short4v*)&yT[((size_t)(b*DIM + d0 + d))*FFT_N + s0 + s4];
        tile[d][s4]  =bf2f((unsigned short)y[0]); tile[d][s4+1]=bf2f((unsigned short)y[1]);
        tile[d][s4+2]=bf2f((unsigned short)y[2]); tile[d][s4+3]=bf2f((unsigned short)y[3]);
    }
    __syncthreads();
    const int sl = t >> 4, d4 = (t & 15) * 4;
    #pragma unroll
    for (int p = 0; p < 4; ++p) {
        const int s = s0 + sl + p*16;
        unsigned short* pv = &vg[((size_t)(b*NS + s))*DIM + d0 + d4];
        short4v v = *(short4v*)pv;
        short4v o;
        #pragma unroll
        for (int j = 0; j < 4; ++j)
            o[j] = (short)f2bf(bf2f((unsigned short)v[j]) * tile[d4+j][sl + p*16]);
        *(short4v*)pv = o;
    }
}

// ---------------------------------------------------------------- bf16 GEMM
// Double-buffered pipeline + XCD swizzle. Grid dim3(4, 256).
// MODE 0: Cb = bf16(val);  MODE 2: Cf = val (fp32)
template<int MODE>
__global__ __launch_bounds__(256)
void gemm_bt_kernel(const unsigned short* __restrict__ A,
                    const unsigned short* __restrict__ BT,
                    const float* __restrict__ bias,
                    float* __restrict__ Cf,
                    unsigned short* __restrict__ Cb) {
    __shared__ unsigned short As[2][4096];
    __shared__ unsigned short Bs[2][4096];
    const int tid = threadIdx.x;
    const int wid = tid >> 6, lane = tid & 63;
    const int bid = blockIdx.y * 4 + blockIdx.x;
    const int swz = (bid & 7) * 128 + (bid >> 3);
    const int m0 = (swz >> 2) * 128, n0 = (swz & 3) * 128;
    const int srow = wid*16 + (lane >> 2);
    const int scol = (lane & 3) * 8;
    const unsigned short* gA = A  + (size_t)(m0 + srow)*DIM + scol;
    const unsigned short* gB = BT + (size_t)(n0 + srow)*DIM + scol;
    const int wr = wid >> 1, wc = wid & 1;
    const int fr = lane & 15, fq = lane >> 4;
    f32x4 acc[4][4] = {};
    gload16(gA,                  &As[0][wid*512]);
    gload16(gA + (size_t)64*DIM, &As[0][wid*512 + 2048]);
    gload16(gB,                  &Bs[0][wid*512]);
    gload16(gB + (size_t)64*DIM, &Bs[0][wid*512 + 2048]);
    int cur = 0;
    for (int k0 = 0; k0 < DIM; k0 += 32) {
        __syncthreads();
        if (k0 + 32 < DIM) {
            const int nx = cur ^ 1;
            gload16(gA + k0 + 32,                  &As[nx][wid*512]);
            gload16(gA + k0 + 32 + (size_t)64*DIM, &As[nx][wid*512 + 2048]);
            gload16(gB + k0 + 32,                  &Bs[nx][wid*512]);
            gload16(gB + k0 + 32 + (size_t)64*DIM, &Bs[nx][wid*512 + 2048]);
        }
        bf16x8 af[4], bfr[4];
        #pragma unroll
        for (int mi = 0; mi < 4; ++mi)
            af[mi] = *(const bf16x8*)&As[cur][(wr*64 + mi*16 + fr)*32 + fq*8];
        #pragma unroll
        for (int ni = 0; ni < 4; ++ni)
            bfr[ni] = *(const bf16x8*)&Bs[cur][(wc*64 + ni*16 + fr)*32 + fq*8];
        #pragma unroll
        for (int mi = 0; mi < 4; ++mi)
            #pragma unroll
            for (int ni = 0; ni < 4; ++ni)
                acc[mi][ni] = __builtin_amdgcn_mfma_f32_16x16x32_bf16(af[mi], bfr[ni], acc[mi][ni], 0, 0, 0);
        cur ^= 1;
    }
    #pragma unroll
    for (int ni = 0; ni < 4; ++ni) {
        const int c = n0 + wc*64 + ni*16 + fr;
        const float bv = bias[c];
        #pragma unroll
        for (int mi = 0; mi < 4; ++mi) {
            const int rbase = m0 + wr*64 + mi*16 + fq*4;
            #pragma unroll
            for (int j = 0; j < 4; ++j) {
                const size_t idx = (size_t)(rbase + j)*DIM + c;
                const float val = acc[mi][ni][j] + bv;
                if (MODE == 0) Cb[idx] = f2bf(val);
                else           Cf[idx] = val;
            }
        }
    }
}

// ------- merged dispatch: blocks 0..1023 -> g0 = (v+bv)*sigmoid(z+bz) (2 accs)
//                          blocks 1024..2047 -> u = x@Wu+bu           (1 acc)
// grid dim3(4, 512). LDS 48KB, block-uniform branch.
__global__ __launch_bounds__(256)
void gemm_vzu2_kernel(const unsigned short* __restrict__ A,
                      const unsigned short* __restrict__ BT,   // w_inT (1536,512)
                      const float* __restrict__ bias,          // b_in (1536)
                      unsigned short* __restrict__ Gb,         // g0 (B,S,D)
                      unsigned short* __restrict__ Ub) {       // u  (B,S,D)
    __shared__ unsigned short As[2][4096];
    __shared__ unsigned short B1[2][4096];
    __shared__ unsigned short B2[2][4096];
    const int tid = threadIdx.x;
    const int wid = tid >> 6, lane = tid & 63;
    const int bid = blockIdx.y * 4 + blockIdx.x;
    const bool is_u = bid >= 1024;
    const int lbid = bid & 1023;
    const int swz = (lbid & 7) * 128 + (lbid >> 3);
    const int m0 = (swz >> 2) * 128, n0 = (swz & 3) * 128;
    const int srow = wid*16 + (lane >> 2);
    const int scol = (lane & 3) * 8;
    const unsigned short* gA = A + (size_t)(m0 + srow)*DIM + scol;
    const int wr = wid >> 1, wc = wid & 1;
    const int fr = lane & 15, fq = lane >> 4;

    if (!is_u) {
        const unsigned short* gBv = BT + (size_t)(n0 + srow)*DIM + scol;
        const unsigned short* gBz = BT + (size_t)(1024 + n0 + srow)*DIM + scol;
        f32x4 accv[4][4] = {};
        f32x4 accz[4][4] = {};
        gload16(gA,                   &As[0][wid*512]);
        gload16(gA  + (size_t)64*DIM, &As[0][wid*512 + 2048]);
        gload16(gBv,                  &B1[0][wid*512]);
        gload16(gBv + (size_t)64*DIM, &B1[0][wid*512 + 2048]);
        gload16(gBz,                  &B2[0][wid*512]);
        gload16(gBz + (size_t)64*DIM, &B2[0][wid*512 + 2048]);
        int cur = 0;
        for (int k0 = 0; k0 < DIM; k0 += 32) {
            __syncthreads();
            if (k0 + 32 < DIM) {
                const int nx = cur ^ 1;
                gload16(gA  + k0 + 32,                  &As[nx][wid*512]);
                gload16(gA  + k0 + 32 + (size_t)64*DIM, &As[nx][wid*512 + 2048]);
                gload16(gBv + k0 + 32,                  &B1[nx][wid*512]);
                gload16(gBv + k0 + 32 + (size_t)64*DIM, &B1[nx][wid*512 + 2048]);
                gload16(gBz + k0 + 32,                  &B2[nx][wid*512]);
                gload16(gBz + k0 + 32 + (size_t)64*DIM, &B2[nx][wid*512 + 2048]);
            }
            bf16x8 af[4], bf_[4];
            #pragma unroll
            for (int mi = 0; mi < 4; ++mi)
                af[mi] = *(const bf16x8*)&As[cur][(wr*64 + mi*16 + fr)*32 + fq*8];
            #pragma unroll
            for (int ni = 0; ni < 4; ++ni)
                bf_[ni] = *(const bf16x8*)&B1[cur][(wc*64 + ni*16 + fr)*32 + fq*8];
            #pragma unroll
            for (int mi = 0; mi < 4; ++mi)
                #pragma unroll
                for (int ni = 0; ni < 4; ++ni)
                    accv[mi][ni] = __builtin_amdgcn_mfma_f32_16x16x32_bf16(af[mi], bf_[ni], accv[mi][ni], 0, 0, 0);
            #pragma unroll
            for (int ni = 0; ni < 4; ++ni)
                bf_[ni] = *(const bf16x8*)&B2[cur][(wc*64 + ni*16 + fr)*32 + fq*8];
            #pragma unroll
            for (int mi = 0; mi < 4; ++mi)
                #pragma unroll
                for (int ni = 0; ni < 4; ++ni)
                    accz[mi][ni] = __builtin_amdgcn_mfma_f32_16x16x32_bf16(af[mi], bf_[ni], accz[mi][ni], 0, 0, 0);
            cur ^= 1;
        }
        #pragma unroll
        for (int ni = 0; ni < 4; ++ni) {
            const int c = n0 + wc*64 + ni*16 + fr;
            const float bv = bias[c];
            const float bz = bias[1024 + c];
            #pragma unroll
            for (int mi = 0; mi < 4; ++mi) {
                const int rbase = m0 + wr*64 + mi*16 + fq*4;
                #pragma unroll
                for (int j = 0; j < 4; ++j) {
                    const size_t idx = (size_t)(rbase + j)*DIM + c;
                    const float vv = accv[mi][ni][j] + bv;
                    const float zz = accz[mi][ni][j] + bz;
                    const float sg = 1.0f / (1.0f + __expf(-zz));
                    Gb[idx] = f2bf(vv * sg);
                }
            }
        }
    } else {
        const unsigned short* gBu = BT + (size_t)(512 + n0 + srow)*DIM + scol;
        f32x4 acc[4][4] = {};
        gload16(gA,                   &As[0][wid*512]);
        gload16(gA  + (size_t)64*DIM, &As[0][wid*512 + 2048]);
        gload16(gBu,                  &B1[0][wid*512]);
        gload16(gBu + (size_t)64*DIM, &B1[0][wid*512 + 2048]);
        int cur = 0;
        for (int k0 = 0; k0 < DIM; k0 += 32) {
            __syncthreads();
            if (k0 + 32 < DIM) {
                const int nx = cur ^ 1;
                gload16(gA  + k0 + 32,                  &As[nx][wid*512]);
                gload16(gA  + k0 + 32 + (size_t)64*DIM, &As[nx][wid*512 + 2048]);
                gload16(gBu + k0 + 32,                  &B1[nx][wid*512]);
                gload16(gBu + k0 + 32 + (size_t)64*DIM, &B1[nx][wid*512 + 2048]);
            }
            bf16x8 af[4], bf_[4];
            #pragma unroll
            for (int mi = 0; mi < 4; ++mi)
                af[mi] = *(const bf16x8*)&As[cur][(wr*64 + mi*16 + fr)*32 + fq*8];
            #pragma unroll
            for (int ni = 0; ni < 4; ++ni)
                bf_[ni] = *(const bf16x8*)&B1[cur][(wc*64 + ni*16 + fr)*32 + fq*8];
            #pragma unroll
            for (int mi = 0; mi < 4; ++mi)
                #pragma unroll
                for (int ni = 0; ni < 4; ++ni)
                    acc[mi][ni] = __builtin_amdgcn_mfma_f32_16x16x32_bf16(af[mi], bf_[ni], acc[mi][ni], 0, 0, 0);
            cur ^= 1;
        }
        #pragma unroll
        for (int ni = 0; ni < 4; ++ni) {
            const int c = n0 + wc*64 + ni*16 + fr;
            const float bu = bias[512 + c];
            #pragma unroll
            for (int mi = 0; mi < 4; ++mi) {
                const int rbase = m0 + wr*64 + mi*16 + fq*4;
                #pragma unroll
                for (int j = 0; j < 4; ++j) {
                    const size_t idx = (size_t)(rbase + j)*DIM + c;
                    Ub[idx] = f2bf(acc[mi][ni][j] + bu);
                }
            }
        }
    }
}

// ---------------------------------------------------------------- launcher
extern "C" void kernel_launch(void* const* d_in, const int* in_sizes, int n_in,
                              void* d_out, int out_size, void* d_ws, size_t ws_size,
                              hipStream_t stream) {
    const float* x      = (const float*)d_in[0];
    const float* w1     = (const float*)d_in[1];
    const float* b1     = (const float*)d_in[2];
    const float* w2     = (const float*)d_in[3];
    const float* b2     = (const float*)d_in[4];
    const float* w3     = (const float*)d_in[5];
    const float* b3     = (const float*)d_in[6];
    const float* conv_w = (const float*)d_in[7];
    const float* conv_b = (const float*)d_in[8];
    const float* w_in   = (const float*)d_in[9];
    const float* b_in   = (const float*)d_in[10];
    const float* w_out  = (const float*)d_in[11];
    const float* b_out  = (const float*)d_in[12];
    float* out = (float*)d_out;

    const size_t NEED = 167772160ULL;              // 160 MiB (known to fit)
    if (ws_size < NEED) return;
    char* ws = (char*)d_ws;
    float2*         Fbr    = (float2*)ws;                               // [0,32M)
    unsigned short* xb     = (unsigned short*)(ws + (size_t)( 32<<20)); // [32,64M) x bf16 -> uT
    unsigned short* W2     = (unsigned short*)(ws + (size_t)( 64<<20)); // [64,96M) g0/g
    unsigned short* W3     = (unsigned short*)(ws + (size_t)( 96<<20)); // [96,128M) u (B,S,D)
    char*           W4     = ws + (size_t)(128<<20);                    // [128,160M)
    unsigned short* w_inT  = (unsigned short*)W4;                       // +0, 1.5 MiB
    unsigned short* w_outT = (unsigned short*)(W4 + (size_t)(2<<20));   // +2M, 0.5 MiB
    float*          filtT  = (float*)(W4 + (size_t)(4<<20));            // +4M, 16 MiB

    // 1. mega prep: cast x -> xb, cast+T weights, filter MLP -> filtT (D,S)
    mega_prep_kernel<<<8576, 256, 0, stream>>>(x, xb, w_in, w_inT, w_out, w_outT,
                                               w1, b1, w2, b2, w3, b3, filtT);
    // 2. merged: g0 -> W2 (1024 blocks), u -> W3 (1024 blocks)
    gemm_vzu2_kernel<<<dim3(4, 512), 256, 0, stream>>>(xb, w_inT, b_in, W2, W3);
    // 3. merged: filter spectrum -> Fbr | depthwise conv + transpose W3 -> xb
    filtconv_kernel<<<4608, FT, 0, stream>>>(filtT, Fbr, W3, conv_w, conv_b, xb);
    // 4. packed FFT circular conv, in-place on xb rows
    fft_conv_kernel<<<(NB/2)*DIM, FT, 0, stream>>>(xb, Fbr);
    // 5. g = g0 * y (transposed read of xb), in-place on W2
    gate_kernel<<<NB*(NS/64)*(DIM/64), 256, 0, stream>>>(W2, xb);
    // 6. out = g @ w_out + b_out -> d_out fp32
    gemm_bt_kernel<2><<<dim3(4, MTOT/128), 256, 0, stream>>>(W2, w_outT, b_out, out, nullptr);
}

// Round 15
// 258.060 us; speedup vs baseline: 1.6771x; 1.6771x over previous
//
#include <hip/hip_runtime.h>
#include <math.h>

#define DIM   512
#define NB    4
#define NS    8192
#define FFT_N 8192
#define FT    1024
#define MTOT  (NB*NS)

// padded LDS index map for FFT: +1 float2 per 8 -> spreads tail/stage banks
#define IDX(i) ((i) + ((i) >> 3))
#define XSZ   9216

typedef __attribute__((ext_vector_type(8))) short bf16x8;
typedef __attribute__((ext_vector_type(4))) short short4v;
typedef __attribute__((ext_vector_type(8))) short short8v;
typedef __attribute__((ext_vector_type(4))) float f32x4;

// ---------------------------------------------------------------- helpers
__device__ __forceinline__ float bf2f(unsigned short u) {
    union { unsigned int i; float f; } v; v.i = ((unsigned int)u) << 16; return v.f;
}
__device__ __forceinline__ unsigned short f2bf(float f) {
    union { float f; unsigned int i; } v; v.f = f;
    unsigned int r = v.i + 0x7fffu + ((v.i >> 16) & 1u);
    return (unsigned short)(r >> 16);
}
__device__ __forceinline__ float2 cmulf(float2 a, float2 b) {
    return make_float2(a.x*b.x - a.y*b.y, a.x*b.y + a.y*b.x);
}
__device__ __forceinline__ float2 cadd(float2 a, float2 b) { return make_float2(a.x+b.x, a.y+b.y); }
__device__ __forceinline__ float2 csub(float2 a, float2 b) { return make_float2(a.x-b.x, a.y-b.y); }
__device__ __forceinline__ float gelu_exact(float x) {
    return 0.5f * x * (1.0f + erff(x * 0.70710678118654752f));
}
__device__ __forceinline__ void gload16(const void* g, void* l) {
    __builtin_amdgcn_global_load_lds((const __attribute__((address_space(1))) void*)g,
                                     (__attribute__((address_space(3))) void*)l, 16, 0, 0);
}

// ------------------------------------------------- fp32 transpose (R,C)->(C,R)
__global__ void transpose_f32_kernel(const float* __restrict__ in, float* __restrict__ out,
                                     int R, int C) {
    __shared__ float tile[64][65];
    const int c0 = blockIdx.x * 64, r0 = blockIdx.y * 64;
    const int t = threadIdx.x;
    const int rr = t >> 4, c4 = (t & 15) * 4;
    #pragma unroll
    for (int p = 0; p < 4; ++p) {
        const int r = rr + p*16;
        float4 v = *(const float4*)&in[(size_t)(r0 + r)*C + c0 + c4];
        tile[r][c4+0]=v.x; tile[r][c4+1]=v.y; tile[r][c4+2]=v.z; tile[r][c4+3]=v.w;
    }
    __syncthreads();
    const int cc = t >> 4, r4 = (t & 15) * 4;
    #pragma unroll
    for (int p = 0; p < 4; ++p) {
        const int c = cc + p*16;
        float4 o = make_float4(tile[r4+0][c], tile[r4+1][c], tile[r4+2][c], tile[r4+3][c]);
        *(float4*)&out[(size_t)(c0 + c)*R + r0 + r4] = o;
    }
}

// ---------------- mega prep: cast_x | castT(w_in) | castT(w_out) | filter MLP
__device__ __forceinline__ void castT_body(const float* __restrict__ in,
                                           unsigned short* __restrict__ outT,
                                           int R, int C, int bx, int by, int t,
                                           float tile[64][65]) {
    const int c0 = bx * 64, r0 = by * 64;
    const int rr = t >> 4, c4 = (t & 15) * 4;
    #pragma unroll
    for (int p = 0; p < 4; ++p) {
        const int r = rr + p*16;
        float4 v = *(const float4*)&in[(size_t)(r0 + r)*C + c0 + c4];
        tile[r][c4+0]=v.x; tile[r][c4+1]=v.y; tile[r][c4+2]=v.z; tile[r][c4+3]=v.w;
    }
    __syncthreads();
    const int cc = t >> 4, r4 = (t & 15) * 4;
    #pragma unroll
    for (int p = 0; p < 4; ++p) {
        const int c = cc + p*16;
        short4v o;
        o[0] = (short)f2bf(tile[r4+0][c]); o[1] = (short)f2bf(tile[r4+1][c]);
        o[2] = (short)f2bf(tile[r4+2][c]); o[3] = (short)f2bf(tile[r4+3][c]);
        *(short4v*)&outT[(size_t)(c0 + c)*R + r0 + r4] = o;
    }
}

__global__ void mega_prep_kernel(const float* __restrict__ x, unsigned short* __restrict__ xb,
                                 const float* __restrict__ w_in, unsigned short* __restrict__ w_inT,
                                 const float* __restrict__ w_out, unsigned short* __restrict__ w_outT,
                                 const float* __restrict__ w1, const float* __restrict__ b1,
                                 const float* __restrict__ w2, const float* __restrict__ b2,
                                 const float* __restrict__ w3, const float* __restrict__ b3,
                                 float* __restrict__ filt) {
    __shared__ float tile[64][65];
    __shared__ float h1s[4][64];
    __shared__ float h2s[4][64];
    const int bid = blockIdx.x;
    const int t = threadIdx.x;
    if (bid < 8192) {
        const size_t i = ((size_t)bid * 256 + t) * 8;
        float4 a = *(const float4*)&x[i];
        float4 b = *(const float4*)&x[i+4];
        short8v o;
        o[0]=(short)f2bf(a.x); o[1]=(short)f2bf(a.y); o[2]=(short)f2bf(a.z); o[3]=(short)f2bf(a.w);
        o[4]=(short)f2bf(b.x); o[5]=(short)f2bf(b.y); o[6]=(short)f2bf(b.z); o[7]=(short)f2bf(b.w);
        *(short8v*)&xb[i] = o;
    } else if (bid < 8384) {
        const int li = bid - 8192;
        castT_body(w_in, w_inT, DIM, 1536, li % 24, li / 24, t, tile);
    } else if (bid < 8448) {
        const int li = bid - 8384;
        castT_body(w_out, w_outT, DIM, DIM, li % 8, li / 8, t, tile);
    } else {
        const int sub = t >> 6, lane = t & 63;
        const int s = (bid - 8448) * 4 + sub;
        const float pos = (float)s / (float)(NS - 1);
        h1s[sub][lane] = gelu_exact(pos * w1[lane] + b1[lane]);
        __syncthreads();
        float acc = b2[lane];
        #pragma unroll 8
        for (int j = 0; j < 64; ++j) acc += h1s[sub][j] * w2[j*64 + lane];
        h2s[sub][lane] = gelu_exact(acc);
        __syncthreads();
        for (int d = lane; d < DIM; d += 64) {
            float o = b3[d];
            #pragma unroll 8
            for (int j = 0; j < 64; ++j) o += h2s[sub][j] * w3[j*DIM + d];
            filt[(size_t)s*DIM + d] = o;
        }
    }
}

// ---------------------------------------------------------------- FFT pieces
template<int LOGQ>
__device__ __forceinline__ void dif4_stage(float2* X) {
    const int q = 1 << LOGQ;
    const float step = -6.28318530717958647692f / (float)(4*q);
    #pragma unroll
    for (int it = 0; it < (FFT_N/4)/FT; ++it) {
        const int idx = threadIdx.x + it*FT;
        const int g = idx >> LOGQ, k = idx & (q-1);
        const int base = (g << (LOGQ+2)) + k;
        const int i0 = IDX(base), i1 = IDX(base+q), i2 = IDX(base+2*q), i3 = IDX(base+3*q);
        float2 a=X[i0], b=X[i1], c=X[i2], d=X[i3];
        float2 t0=cadd(a,c), t1=csub(a,c), t2=cadd(b,d), t3=csub(b,d);
        float2 y0=cadd(t0,t2), y2=csub(t0,t2);
        float2 y1=make_float2(t1.x+t3.y, t1.y-t3.x);   // t1 - i*t3
        float2 y3=make_float2(t1.x-t3.y, t1.y+t3.x);   // t1 + i*t3
        float sv, cv; __sincosf(step*(float)k, &sv, &cv);
        float2 w1=make_float2(cv, sv);
        float2 w2=cmulf(w1, w1);
        float2 w3=cmulf(w2, w1);
        X[i0] = y0;
        X[i1] = cmulf(y1, w1);
        X[i2] = cmulf(y2, w2);
        X[i3] = cmulf(y3, w3);
    }
    __syncthreads();
}

template<int LOGQ>
__device__ __forceinline__ void dit4_stage_inv(float2* X) {
    const int q = 1 << LOGQ;
    const float step = 6.28318530717958647692f / (float)(4*q);
    #pragma unroll
    for (int it = 0; it < (FFT_N/4)/FT; ++it) {
        const int idx = threadIdx.x + it*FT;
        const int g = idx >> LOGQ, k = idx & (q-1);
        const int base = (g << (LOGQ+2)) + k;
        const int i0 = IDX(base), i1 = IDX(base+q), i2 = IDX(base+2*q), i3 = IDX(base+3*q);
        float sv, cv; __sincosf(step*(float)k, &sv, &cv);
        float2 w1=make_float2(cv, sv);
        float2 w2=cmulf(w1, w1);
        float2 w3=cmulf(w2, w1);
        float2 u0=X[i0];
        float2 u1=cmulf(X[i1], w1);
        float2 u2=cmulf(X[i2], w2);
        float2 u3=cmulf(X[i3], w3);
        float2 s02=cadd(u0,u2), d02=csub(u0,u2);
        float2 s13=cadd(u1,u3), d13=csub(u1,u3);
        X[i0] = cadd(s02, s13);
        X[i2] = csub(s02, s13);
        X[i1] = make_float2(d02.x - d13.y, d02.y + d13.x);   // d02 + i*d13
        X[i3] = make_float2(d02.x + d13.y, d02.y - d13.x);   // d02 - i*d13
    }
    __syncthreads();
}

__device__ __forceinline__ void reg_fwd(float2* E) {
    const float C = 0.70710678118654752f;
    {
        float2 t0=cadd(E[0],E[4]), t1=csub(E[0],E[4]);
        float2 t2=cadd(E[2],E[6]), t3=csub(E[2],E[6]);
        E[0]=cadd(t0,t2);
        E[4]=csub(t0,t2);
        E[2]=make_float2(t1.x+t3.y, t1.y-t3.x);
        E[6]=make_float2(t1.x-t3.y, t1.y+t3.x);
    }
    {
        float2 t0=cadd(E[1],E[5]), t1=csub(E[1],E[5]);
        float2 t2=cadd(E[3],E[7]), t3=csub(E[3],E[7]);
        float2 y0=cadd(t0,t2), y2=csub(t0,t2);
        float2 y1=make_float2(t1.x+t3.y, t1.y-t3.x);
        float2 y3=make_float2(t1.x-t3.y, t1.y+t3.x);
        E[1]=y0;
        E[3]=make_float2(C*(y1.x+y1.y),  C*(y1.y-y1.x));
        E[5]=make_float2(y2.y, -y2.x);
        E[7]=make_float2(C*(y3.y-y3.x), -C*(y3.x+y3.y));
    }
    #pragma unroll
    for (int j = 0; j < 8; j += 2) {
        float2 a=E[j], b=E[j+1];
        E[j]=cadd(a,b); E[j+1]=csub(a,b);
    }
}
__device__ __forceinline__ void reg_inv(float2* E) {
    const float C = 0.70710678118654752f;
    #pragma unroll
    for (int j = 0; j < 8; j += 2) {
        float2 a=E[j], b=E[j+1];
        E[j]=cadd(a,b); E[j+1]=csub(a,b);
    }
    {
        float2 u0=E[0], u1=E[2], u2=E[4], u3=E[6];
        float2 s02=cadd(u0,u2), d02=csub(u0,u2);
        float2 s13=cadd(u1,u3), d13=csub(u1,u3);
        E[0]=cadd(s02,s13);
        E[4]=csub(s02,s13);
        E[2]=make_float2(d02.x - d13.y, d02.y + d13.x);
        E[6]=make_float2(d02.x + d13.y, d02.y - d13.x);
    }
    {
        float2 z1=E[3], z2=E[5], z3=E[7];
        float2 u0=E[1];
        float2 u1=make_float2(C*(z1.x - z1.y), C*(z1.x + z1.y));
        float2 u2=make_float2(-z2.y, z2.x);
        float2 u3=make_float2(-C*(z3.x + z3.y), C*(z3.x - z3.y));
        float2 s02=cadd(u0,u2), d02=csub(u0,u2);
        float2 s13=cadd(u1,u3), d13=csub(u1,u3);
        E[1]=cadd(s02,s13);
        E[5]=csub(s02,s13);
        E[3]=make_float2(d02.x - d13.y, d02.y + d13.x);
        E[7]=make_float2(d02.x + d13.y, d02.y - d13.x);
    }
}

// thread t owns logical elems 8t..8t+7 == phys 9t..9t+7 (contiguous)
__device__ __forceinline__ void load8p(const float2* X, int t, float2* E) {
    const float2* b = X + 9*t;
    #pragma unroll
    for (int j = 0; j < 8; ++j) E[j] = b[j];
}
__device__ __forceinline__ void store8p(float2* X, int t, const float2* E) {
    float2* b = X + 9*t;
    #pragma unroll
    for (int j = 0; j < 8; ++j) b[j] = E[j];
}

// -------- merged 1024-thread dispatch: blocks [0,512) fft_filt, [512,4608) conv+T
__global__ __launch_bounds__(FT)
void filtconv_kernel(const float* __restrict__ filtT, float2* __restrict__ Fbr,
                     const unsigned short* __restrict__ u,
                     const float* __restrict__ conv_w, const float* __restrict__ conv_b,
                     unsigned short* __restrict__ uT) {
    __shared__ __align__(16) char fsm[XSZ * sizeof(float2)];   // 72 KB union
    const int bid = blockIdx.x;
    const int t = threadIdx.x;
    if (bid < 512) {
        float2* X = (float2*)fsm;
        const int dd = bid;
        const float* f = filtT + (size_t)dd * FFT_N;
        {
            float4 a = *(const float4*)(f + 8*t);
            float4 b = *(const float4*)(f + 8*t + 4);
            float2 E[8];
            E[0]=make_float2(a.x,0.f); E[1]=make_float2(a.y,0.f);
            E[2]=make_float2(a.z,0.f); E[3]=make_float2(a.w,0.f);
            E[4]=make_float2(b.x,0.f); E[5]=make_float2(b.y,0.f);
            E[6]=make_float2(b.z,0.f); E[7]=make_float2(b.w,0.f);
            store8p(X, t, E);
        }
        __syncthreads();
        dif4_stage<11>(X);
        dif4_stage<9>(X);
        dif4_stage<7>(X);
        dif4_stage<5>(X);
        dif4_stage<3>(X);
        {
            float2 E[8];
            load8p(X, t, E);
            reg_fwd(E);
            float2* o = Fbr + (size_t)dd*FFT_N + 8*t;
            #pragma unroll
            for (int j = 0; j < 8; ++j) o[j] = E[j];
        }
    } else {
        float (*tile)[65] = (float(*)[65])fsm;                 // [66][65] = 16.8 KB
        const int lb = bid - 512;
        const int dt = lb & 7, st = (lb >> 3) & 127, b = lb >> 10;
        const int d0 = dt*64, s0 = st*64;
        const int rr = t >> 4, c4 = (t & 15) * 4;
        for (int r = rr; r < 66; r += 64) {
            const int s = s0 + r - 1;
            float v0=0.f, v1=0.f, v2=0.f, v3=0.f;
            if (s >= 0 && s < NS) {
                short4v xv = *(const short4v*)&u[((size_t)(b*NS + s))*DIM + d0 + c4];
                v0=bf2f((unsigned short)xv[0]); v1=bf2f((unsigned short)xv[1]);
                v2=bf2f((unsigned short)xv[2]); v3=bf2f((unsigned short)xv[3]);
            }
            tile[r][c4]=v0; tile[r][c4+1]=v1; tile[r][c4+2]=v2; tile[r][c4+3]=v3;
        }
        __syncthreads();
        const int dc = t >> 4, s4 = (t & 15) * 4;
        const int d = d0 + dc;
        const float w0 = conv_w[d*3], w1 = conv_w[d*3+1], w2 = conv_w[d*3+2];
        const float cb = conv_b[d];
        short4v o;
        #pragma unroll
        for (int j = 0; j < 4; ++j) {
            const int sx = s4 + j;
            const float val = tile[sx][dc]*w0 + tile[sx+1][dc]*w1 + tile[sx+2][dc]*w2 + cb;
            o[j] = (short)f2bf(val);
        }
        *(short4v*)&uT[((size_t)(b*DIM + d))*FFT_N + s0 + s4] = o;
    }
}

// packed-pair circular conv, in-place bf16: rows (2p,d) and (2p+1,d) of uT
__global__ __launch_bounds__(FT)
void fft_conv_kernel(unsigned short* __restrict__ uT, const float2* __restrict__ Fbr) {
    __shared__ float2 X[XSZ];
    const int d = blockIdx.x & (DIM - 1);
    const int p = blockIdx.x >> 9;
    unsigned short* u1 = uT + (size_t)((2*p    )*DIM + d) * FFT_N;
    unsigned short* u2 = uT + (size_t)((2*p + 1)*DIM + d) * FFT_N;
    const int t = threadIdx.x;
    {
        short8v a = *(const short8v*)(u1 + 8*t);
        short8v b = *(const short8v*)(u2 + 8*t);
        float2 E[8];
        #pragma unroll
        for (int j = 0; j < 8; ++j)
            E[j] = make_float2(bf2f((unsigned short)a[j]), bf2f((unsigned short)b[j]));
        store8p(X, t, E);
    }
    __syncthreads();
    dif4_stage<11>(X);
    dif4_stage<9>(X);
    dif4_stage<7>(X);
    dif4_stage<5>(X);
    dif4_stage<3>(X);
    {
        float2 E[8];
        load8p(X, t, E);
        reg_fwd(E);
        const float2* F = Fbr + (size_t)d*FFT_N + 8*t;
        #pragma unroll
        for (int j = 0; j < 8; ++j) E[j] = cmulf(E[j], F[j]);
        reg_inv(E);
        store8p(X, t, E);
    }
    __syncthreads();
    dit4_stage_inv<3>(X);
    dit4_stage_inv<5>(X);
    dit4_stage_inv<7>(X);
    dit4_stage_inv<9>(X);
    dit4_stage_inv<11>(X);
    {
        float2 E[8];
        load8p(X, t, E);
        const float sc = 1.0f / (float)FFT_N;
        short8v a, b;
        #pragma unroll
        for (int j = 0; j < 8; ++j) {
            a[j] = (short)f2bf(E[j].x * sc);
            b[j] = (short)f2bf(E[j].y * sc);
        }
        *(short8v*)(u1 + 8*t) = a;
        *(short8v*)(u2 + 8*t) = b;
    }
}

// ---------------------------------------------------------------- gating
__global__ void gate_kernel(unsigned short* __restrict__ vg, const unsigned short* __restrict__ yT) {
    __shared__ float tile[64][65];
    const int bid = blockIdx.x;
    const int dt = bid & 7, st = (bid >> 3) & 127, b = bid >> 10;
    const int d0 = dt*64, s0 = st*64;
    const int t = threadIdx.x;
    const int dl = t >> 4, s4 = (t & 15) * 4;
    #pragma unroll
    for (int p = 0; p < 4; ++p) {
        const int d = dl + p*16;
        short4v y = *(const short4v*)&yT[((size_t)(b*DIM + d0 + d))*FFT_N + s0 + s4];
        tile[d][s4]  =bf2f((unsigned short)y[0]); tile[d][s4+1]=bf2f((unsigned short)y[1]);
        tile[d][s4+2]=bf2f((unsigned short)y[2]); tile[d][s4+3]=bf2f((unsigned short)y[3]);
    }
    __syncthreads();
    const int sl = t >> 4, d4 = (t & 15) * 4;
    #pragma unroll
    for (int p = 0; p < 4; ++p) {
        const int s = s0 + sl + p*16;
        unsigned short* pv = &vg[((size_t)(b*NS + s))*DIM + d0 + d4];
        short4v v = *(short4v*)pv;
        short4v o;
        #pragma unroll
        for (int j = 0; j < 4; ++j)
            o[j] = (short)f2bf(bf2f((unsigned short)v[j]) * tile[d4+j][sl + p*16]);
        *(short4v*)pv = o;
    }
}

// ---------------------------------------------------------------- bf16 GEMM
// Double-buffered pipeline + XCD swizzle. Grid dim3(4, 256).
// MODE 0: Cb = bf16(val);  MODE 2: Cf = val (fp32)
template<int MODE>
__global__ __launch_bounds__(256)
void gemm_bt_kernel(const unsigned short* __restrict__ A,
                    const unsigned short* __restrict__ BT,
                    const float* __restrict__ bias,
                    float* __restrict__ Cf,
                    unsigned short* __restrict__ Cb) {
    __shared__ unsigned short As[2][4096];
    __shared__ unsigned short Bs[2][4096];
    const int tid = threadIdx.x;
    const int wid = tid >> 6, lane = tid & 63;
    const int bid = blockIdx.y * 4 + blockIdx.x;
    const int swz = (bid & 7) * 128 + (bid >> 3);
    const int m0 = (swz >> 2) * 128, n0 = (swz & 3) * 128;
    const int srow = wid*16 + (lane >> 2);
    const int scol = (lane & 3) * 8;
    const unsigned short* gA = A  + (size_t)(m0 + srow)*DIM + scol;
    const unsigned short* gB = BT + (size_t)(n0 + srow)*DIM + scol;
    const int wr = wid >> 1, wc = wid & 1;
    const int fr = lane & 15, fq = lane >> 4;
    f32x4 acc[4][4] = {};
    gload16(gA,                  &As[0][wid*512]);
    gload16(gA + (size_t)64*DIM, &As[0][wid*512 + 2048]);
    gload16(gB,                  &Bs[0][wid*512]);
    gload16(gB + (size_t)64*DIM, &Bs[0][wid*512 + 2048]);
    int cur = 0;
    for (int k0 = 0; k0 < DIM; k0 += 32) {
        __syncthreads();
        if (k0 + 32 < DIM) {
            const int nx = cur ^ 1;
            gload16(gA + k0 + 32,                  &As[nx][wid*512]);
            gload16(gA + k0 + 32 + (size_t)64*DIM, &As[nx][wid*512 + 2048]);
            gload16(gB + k0 + 32,                  &Bs[nx][wid*512]);
            gload16(gB + k0 + 32 + (size_t)64*DIM, &Bs[nx][wid*512 + 2048]);
        }
        bf16x8 af[4], bfr[4];
        #pragma unroll
        for (int mi = 0; mi < 4; ++mi)
            af[mi] = *(const bf16x8*)&As[cur][(wr*64 + mi*16 + fr)*32 + fq*8];
        #pragma unroll
        for (int ni = 0; ni < 4; ++ni)
            bfr[ni] = *(const bf16x8*)&Bs[cur][(wc*64 + ni*16 + fr)*32 + fq*8];
        #pragma unroll
        for (int mi = 0; mi < 4; ++mi)
            #pragma unroll
            for (int ni = 0; ni < 4; ++ni)
                acc[mi][ni] = __builtin_amdgcn_mfma_f32_16x16x32_bf16(af[mi], bfr[ni], acc[mi][ni], 0, 0, 0);
        cur ^= 1;
    }
    #pragma unroll
    for (int ni = 0; ni < 4; ++ni) {
        const int c = n0 + wc*64 + ni*16 + fr;
        const float bv = bias[c];
        #pragma unroll
        for (int mi = 0; mi < 4; ++mi) {
            const int rbase = m0 + wr*64 + mi*16 + fq*4;
            #pragma unroll
            for (int j = 0; j < 4; ++j) {
                const size_t idx = (size_t)(rbase + j)*DIM + c;
                const float val = acc[mi][ni][j] + bv;
                if (MODE == 0) Cb[idx] = f2bf(val);
                else           Cf[idx] = val;
            }
        }
    }
}

// ------- merged dispatch: blocks 0..1023 -> g0 = (v+bv)*sigmoid(z+bz) (2 accs)
//                          blocks 1024..2047 -> u = x@Wu+bu           (1 acc)
// grid dim3(4, 512). LDS 48KB, block-uniform branch.
__global__ __launch_bounds__(256)
void gemm_vzu2_kernel(const unsigned short* __restrict__ A,
                      const unsigned short* __restrict__ BT,   // w_inT (1536,512)
                      const float* __restrict__ bias,          // b_in (1536)
                      unsigned short* __restrict__ Gb,         // g0 (B,S,D)
                      unsigned short* __restrict__ Ub) {       // u  (B,S,D)
    __shared__ unsigned short As[2][4096];
    __shared__ unsigned short B1[2][4096];
    __shared__ unsigned short B2[2][4096];
    const int tid = threadIdx.x;
    const int wid = tid >> 6, lane = tid & 63;
    const int bid = blockIdx.y * 4 + blockIdx.x;
    const bool is_u = bid >= 1024;
    const int lbid = bid & 1023;
    const int swz = (lbid & 7) * 128 + (lbid >> 3);
    const int m0 = (swz >> 2) * 128, n0 = (swz & 3) * 128;
    const int srow = wid*16 + (lane >> 2);
    const int scol = (lane & 3) * 8;
    const unsigned short* gA = A + (size_t)(m0 + srow)*DIM + scol;
    const int wr = wid >> 1, wc = wid & 1;
    const int fr = lane & 15, fq = lane >> 4;

    if (!is_u) {
        const unsigned short* gBv = BT + (size_t)(n0 + srow)*DIM + scol;
        const unsigned short* gBz = BT + (size_t)(1024 + n0 + srow)*DIM + scol;
        f32x4 accv[4][4] = {};
        f32x4 accz[4][4] = {};
        gload16(gA,                   &As[0][wid*512]);
        gload16(gA  + (size_t)64*DIM, &As[0][wid*512 + 2048]);
        gload16(gBv,                  &B1[0][wid*512]);
        gload16(gBv + (size_t)64*DIM, &B1[0][wid*512 + 2048]);
        gload16(gBz,                  &B2[0][wid*512]);
        gload16(gBz + (size_t)64*DIM, &B2[0][wid*512 + 2048]);
        int cur = 0;
        for (int k0 = 0; k0 < DIM; k0 += 32) {
            __syncthreads();
            if (k0 + 32 < DIM) {
                const int nx = cur ^ 1;
                gload16(gA  + k0 + 32,                  &As[nx][wid*512]);
                gload16(gA  + k0 + 32 + (size_t)64*DIM, &As[nx][wid*512 + 2048]);
                gload16(gBv + k0 + 32,                  &B1[nx][wid*512]);
                gload16(gBv + k0 + 32 + (size_t)64*DIM, &B1[nx][wid*512 + 2048]);
                gload16(gBz + k0 + 32,                  &B2[nx][wid*512]);
                gload16(gBz + k0 + 32 + (size_t)64*DIM, &B2[nx][wid*512 + 2048]);
            }
            bf16x8 af[4], bf_[4];
            #pragma unroll
            for (int mi = 0; mi < 4; ++mi)
                af[mi] = *(const bf16x8*)&As[cur][(wr*64 + mi*16 + fr)*32 + fq*8];
            #pragma unroll
            for (int ni = 0; ni < 4; ++ni)
                bf_[ni] = *(const bf16x8*)&B1[cur][(wc*64 + ni*16 + fr)*32 + fq*8];
            #pragma unroll
            for (int mi = 0; mi < 4; ++mi)
                #pragma unroll
                for (int ni = 0; ni < 4; ++ni)
                    accv[mi][ni] = __builtin_amdgcn_mfma_f32_16x16x32_bf16(af[mi], bf_[ni], accv[mi][ni], 0, 0, 0);
            #pragma unroll
            for (int ni = 0; ni < 4; ++ni)
                bf_[ni] = *(const bf16x8*)&B2[cur][(wc*64 + ni*16 + fr)*32 + fq*8];
            #pragma unroll
            for (int mi = 0; mi < 4; ++mi)
                #pragma unroll
                for (int ni = 0; ni < 4; ++ni)
                    accz[mi][ni] = __builtin_amdgcn_mfma_f32_16x16x32_bf16(af[mi], bf_[ni], accz[mi][ni], 0, 0, 0);
            cur ^= 1;
        }
        #pragma unroll
        for (int ni = 0; ni < 4; ++ni) {
            const int c = n0 + wc*64 + ni*16 + fr;
            const float bv = bias[c];
            const float bz = bias[1024 + c];
            #pragma unroll
            for (int mi = 0; mi < 4; ++mi) {
                const int rbase = m0 + wr*64 + mi*16 + fq*4;
                #pragma unroll
                for (int j = 0; j < 4; ++j) {
                    const size_t idx = (size_t)(rbase + j)*DIM + c;
                    const float vv = accv[mi][ni][j] + bv;
                    const float zz = accz[mi][ni][j] + bz;
                    const float sg = 1.0f / (1.0f + __expf(-zz));
                    Gb[idx] = f2bf(vv * sg);
                }
            }
        }
    } else {
        const unsigned short* gBu = BT + (size_t)(512 + n0 + srow)*DIM + scol;
        f32x4 acc[4][4] = {};
        gload16(gA,                   &As[0][wid*512]);
        gload16(gA  + (size_t)64*DIM, &As[0][wid*512 + 2048]);
        gload16(gBu,                  &B1[0][wid*512]);
        gload16(gBu + (size_t)64*DIM, &B1[0][wid*512 + 2048]);
        int cur = 0;
        for (int k0 = 0; k0 < DIM; k0 += 32) {
            __syncthreads();
            if (k0 + 32 < DIM) {
                const int nx = cur ^ 1;
                gload16(gA  + k0 + 32,                  &As[nx][wid*512]);
                gload16(gA  + k0 + 32 + (size_t)64*DIM, &As[nx][wid*512 + 2048]);
                gload16(gBu + k0 + 32,                  &B1[nx][wid*512]);
                gload16(gBu + k0 + 32 + (size_t)64*DIM, &B1[nx][wid*512 + 2048]);
            }
            bf16x8 af[4], bf_[4];
            #pragma unroll
            for (int mi = 0; mi < 4; ++mi)
                af[mi] = *(const bf16x8*)&As[cur][(wr*64 + mi*16 + fr)*32 + fq*8];
            #pragma unroll
            for (int ni = 0; ni < 4; ++ni)
                bf_[ni] = *(const bf16x8*)&B1[cur][(wc*64 + ni*16 + fr)*32 + fq*8];
            #pragma unroll
            for (int mi = 0; mi < 4; ++mi)
                #pragma unroll
                for (int ni = 0; ni < 4; ++ni)
                    acc[mi][ni] = __builtin_amdgcn_mfma_f32_16x16x32_bf16(af[mi], bf_[ni], acc[mi][ni], 0, 0, 0);
            cur ^= 1;
        }
        #pragma unroll
        for (int ni = 0; ni < 4; ++ni) {
            const int c = n0 + wc*64 + ni*16 + fr;
            const float bu = bias[512 + c];
            #pragma unroll
            for (int mi = 0; mi < 4; ++mi) {
                const int rbase = m0 + wr*64 + mi*16 + fq*4;
                #pragma unroll
                for (int j = 0; j < 4; ++j) {
                    const size_t idx = (size_t)(rbase + j)*DIM + c;
                    Ub[idx] = f2bf(acc[mi][ni][j] + bu);
                }
            }
        }
    }
}

// ---------------------------------------------------------------- launcher
extern "C" void kernel_launch(void* const* d_in, const int* in_sizes, int n_in,
                              void* d_out, int out_size, void* d_ws, size_t ws_size,
                              hipStream_t stream) {
    const float* x      = (const float*)d_in[0];
    const float* w1     = (const float*)d_in[1];
    const float* b1     = (const float*)d_in[2];
    const float* w2     = (const float*)d_in[3];
    const float* b2     = (const float*)d_in[4];
    const float* w3     = (const float*)d_in[5];
    const float* b3     = (const float*)d_in[6];
    const float* conv_w = (const float*)d_in[7];
    const float* conv_b = (const float*)d_in[8];
    const float* w_in   = (const float*)d_in[9];
    const float* b_in   = (const float*)d_in[10];
    const float* w_out  = (const float*)d_in[11];
    const float* b_out  = (const float*)d_in[12];
    float* out = (float*)d_out;

    const size_t NEED = 167772160ULL;              // 160 MiB (known to fit)
    if (ws_size < NEED) return;
    char* ws = (char*)d_ws;
    float2*         Fbr    = (float2*)ws;                               // [0,32M)
    unsigned short* xb     = (unsigned short*)(ws + (size_t)( 32<<20)); // [32,64M) x bf16 -> uT
    unsigned short* W2     = (unsigned short*)(ws + (size_t)( 64<<20)); // [64,96M) filt -> g0/g
    unsigned short* W3     = (unsigned short*)(ws + (size_t)( 96<<20)); // [96,128M) u (B,S,D)
    char*           W4     = ws + (size_t)(128<<20);                    // [128,160M)
    unsigned short* w_inT  = (unsigned short*)W4;                       // +0, 1.5 MiB
    unsigned short* w_outT = (unsigned short*)(W4 + (size_t)(2<<20));   // +2M, 0.5 MiB
    float*          filtT  = (float*)(W4 + (size_t)(4<<20));            // +4M, 16 MiB (private)
    float*          filt   = (float*)W2;                                // dead before g0 written

    // 1. mega prep: cast x -> xb, cast+T weights, filter MLP -> filt (S,D)
    mega_prep_kernel<<<10496, 256, 0, stream>>>(x, xb, w_in, w_inT, w_out, w_outT,
                                                w1, b1, w2, b2, w3, b3, filt);
    // 2. transpose filt (NS,DIM)@W2 -> filtT (DIM,NS)@W4+4M
    transpose_f32_kernel<<<dim3(DIM/64, NS/64), 256, 0, stream>>>(filt, filtT, NS, DIM);
    // 3. merged: g0 -> W2 (overwrites filt, already consumed), u -> W3
    gemm_vzu2_kernel<<<dim3(4, 512), 256, 0, stream>>>(xb, w_inT, b_in, W2, W3);
    // 4. merged: filter spectrum filtT -> Fbr | depthwise conv + transpose W3 -> xb
    filtconv_kernel<<<4608, FT, 0, stream>>>(filtT, Fbr, W3, conv_w, conv_b, xb);
    // 5. packed FFT circular conv, in-place on xb rows
    fft_conv_kernel<<<(NB/2)*DIM, FT, 0, stream>>>(xb, Fbr);
    // 6. g = g0 * y (transposed read of xb), in-place on W2
    gate_kernel<<<NB*(NS/64)*(DIM/64), 256, 0, stream>>>(W2, xb);
    // 7. out = g @ w_out + b_out -> d_out fp32
    gemm_bt_kernel<2><<<dim3(4, MTOT/128), 256, 0, stream>>>(W2, w_outT, b_out, out, nullptr);
}

// Round 16
// 257.445 us; speedup vs baseline: 1.6811x; 1.0024x over previous
//
#include <hip/hip_runtime.h>
#include <math.h>

#define DIM   512
#define NB    4
#define NS    8192
#define FFT_N 8192
#define FT    1024
#define MTOT  (NB*NS)

// padded LDS index map for FFT: +1 float2 per 8 -> spreads tail/stage banks
#define IDX(i) ((i) + ((i) >> 3))
#define XSZ   9216

typedef __attribute__((ext_vector_type(8))) short bf16x8;
typedef __attribute__((ext_vector_type(4))) short short4v;
typedef __attribute__((ext_vector_type(8))) short short8v;
typedef __attribute__((ext_vector_type(4))) float f32x4;

// ---------------------------------------------------------------- helpers
__device__ __forceinline__ float bf2f(unsigned short u) {
    union { unsigned int i; float f; } v; v.i = ((unsigned int)u) << 16; return v.f;
}
__device__ __forceinline__ unsigned short f2bf(float f) {
    union { float f; unsigned int i; } v; v.f = f;
    unsigned int r = v.i + 0x7fffu + ((v.i >> 16) & 1u);
    return (unsigned short)(r >> 16);
}
__device__ __forceinline__ float2 cmulf(float2 a, float2 b) {
    return make_float2(a.x*b.x - a.y*b.y, a.x*b.y + a.y*b.x);
}
__device__ __forceinline__ float2 cadd(float2 a, float2 b) { return make_float2(a.x+b.x, a.y+b.y); }
__device__ __forceinline__ float2 csub(float2 a, float2 b) { return make_float2(a.x-b.x, a.y-b.y); }
__device__ __forceinline__ float gelu_exact(float x) {
    return 0.5f * x * (1.0f + erff(x * 0.70710678118654752f));
}
__device__ __forceinline__ void gload16(const void* g, void* l) {
    __builtin_amdgcn_global_load_lds((const __attribute__((address_space(1))) void*)g,
                                     (__attribute__((address_space(3))) void*)l, 16, 0, 0);
}

// ---------------- mega prep: cast_x | castT(w_in) | castT(w_out) | filter MLP
__device__ __forceinline__ void castT_body(const float* __restrict__ in,
                                           unsigned short* __restrict__ outT,
                                           int R, int C, int bx, int by, int t,
                                           float tile[64][65]) {
    const int c0 = bx * 64, r0 = by * 64;
    const int rr = t >> 4, c4 = (t & 15) * 4;
    #pragma unroll
    for (int p = 0; p < 4; ++p) {
        const int r = rr + p*16;
        float4 v = *(const float4*)&in[(size_t)(r0 + r)*C + c0 + c4];
        tile[r][c4+0]=v.x; tile[r][c4+1]=v.y; tile[r][c4+2]=v.z; tile[r][c4+3]=v.w;
    }
    __syncthreads();
    const int cc = t >> 4, r4 = (t & 15) * 4;
    #pragma unroll
    for (int p = 0; p < 4; ++p) {
        const int c = cc + p*16;
        short4v o;
        o[0] = (short)f2bf(tile[r4+0][c]); o[1] = (short)f2bf(tile[r4+1][c]);
        o[2] = (short)f2bf(tile[r4+2][c]); o[3] = (short)f2bf(tile[r4+3][c]);
        *(short4v*)&outT[(size_t)(c0 + c)*R + r0 + r4] = o;
    }
}

__global__ void mega_prep_kernel(const float* __restrict__ x, unsigned short* __restrict__ xb,
                                 const float* __restrict__ w_in, unsigned short* __restrict__ w_inT,
                                 const float* __restrict__ w_out, unsigned short* __restrict__ w_outT,
                                 const float* __restrict__ w1, const float* __restrict__ b1,
                                 const float* __restrict__ w2, const float* __restrict__ b2,
                                 const float* __restrict__ w3, const float* __restrict__ b3,
                                 float* __restrict__ filt) {
    __shared__ float tile[64][65];
    __shared__ float h1s[4][64];
    __shared__ float h2s[4][64];
    const int bid = blockIdx.x;
    const int t = threadIdx.x;
    if (bid < 8192) {
        const size_t i = ((size_t)bid * 256 + t) * 8;
        float4 a = *(const float4*)&x[i];
        float4 b = *(const float4*)&x[i+4];
        short8v o;
        o[0]=(short)f2bf(a.x); o[1]=(short)f2bf(a.y); o[2]=(short)f2bf(a.z); o[3]=(short)f2bf(a.w);
        o[4]=(short)f2bf(b.x); o[5]=(short)f2bf(b.y); o[6]=(short)f2bf(b.z); o[7]=(short)f2bf(b.w);
        *(short8v*)&xb[i] = o;
    } else if (bid < 8384) {
        const int li = bid - 8192;
        castT_body(w_in, w_inT, DIM, 1536, li % 24, li / 24, t, tile);
    } else if (bid < 8448) {
        const int li = bid - 8384;
        castT_body(w_out, w_outT, DIM, DIM, li % 8, li / 8, t, tile);
    } else {
        const int sub = t >> 6, lane = t & 63;
        const int s = (bid - 8448) * 4 + sub;
        const float pos = (float)s / (float)(NS - 1);
        h1s[sub][lane] = gelu_exact(pos * w1[lane] + b1[lane]);
        __syncthreads();
        float acc = b2[lane];
        #pragma unroll 8
        for (int j = 0; j < 64; ++j) acc += h1s[sub][j] * w2[j*64 + lane];
        h2s[sub][lane] = gelu_exact(acc);
        __syncthreads();
        for (int d = lane; d < DIM; d += 64) {
            float o = b3[d];
            #pragma unroll 8
            for (int j = 0; j < 64; ++j) o += h2s[sub][j] * w3[j*DIM + d];
            filt[(size_t)s*DIM + d] = o;
        }
    }
}

// ---------------------------------------------------------------- FFT pieces
template<int LOGQ>
__device__ __forceinline__ void dif4_stage(float2* X) {
    const int q = 1 << LOGQ;
    const float step = -6.28318530717958647692f / (float)(4*q);
    #pragma unroll
    for (int it = 0; it < (FFT_N/4)/FT; ++it) {
        const int idx = threadIdx.x + it*FT;
        const int g = idx >> LOGQ, k = idx & (q-1);
        const int base = (g << (LOGQ+2)) + k;
        const int i0 = IDX(base), i1 = IDX(base+q), i2 = IDX(base+2*q), i3 = IDX(base+3*q);
        float2 a=X[i0], b=X[i1], c=X[i2], d=X[i3];
        float2 t0=cadd(a,c), t1=csub(a,c), t2=cadd(b,d), t3=csub(b,d);
        float2 y0=cadd(t0,t2), y2=csub(t0,t2);
        float2 y1=make_float2(t1.x+t3.y, t1.y-t3.x);   // t1 - i*t3
        float2 y3=make_float2(t1.x-t3.y, t1.y+t3.x);   // t1 + i*t3
        float sv, cv; __sincosf(step*(float)k, &sv, &cv);
        float2 w1=make_float2(cv, sv);
        float2 w2=cmulf(w1, w1);
        float2 w3=cmulf(w2, w1);
        X[i0] = y0;
        X[i1] = cmulf(y1, w1);
        X[i2] = cmulf(y2, w2);
        X[i3] = cmulf(y3, w3);
    }
    __syncthreads();
}

template<int LOGQ>
__device__ __forceinline__ void dit4_stage_inv(float2* X) {
    const int q = 1 << LOGQ;
    const float step = 6.28318530717958647692f / (float)(4*q);
    #pragma unroll
    for (int it = 0; it < (FFT_N/4)/FT; ++it) {
        const int idx = threadIdx.x + it*FT;
        const int g = idx >> LOGQ, k = idx & (q-1);
        const int base = (g << (LOGQ+2)) + k;
        const int i0 = IDX(base), i1 = IDX(base+q), i2 = IDX(base+2*q), i3 = IDX(base+3*q);
        float sv, cv; __sincosf(step*(float)k, &sv, &cv);
        float2 w1=make_float2(cv, sv);
        float2 w2=cmulf(w1, w1);
        float2 w3=cmulf(w2, w1);
        float2 u0=X[i0];
        float2 u1=cmulf(X[i1], w1);
        float2 u2=cmulf(X[i2], w2);
        float2 u3=cmulf(X[i3], w3);
        float2 s02=cadd(u0,u2), d02=csub(u0,u2);
        float2 s13=cadd(u1,u3), d13=csub(u1,u3);
        X[i0] = cadd(s02, s13);
        X[i2] = csub(s02, s13);
        X[i1] = make_float2(d02.x - d13.y, d02.y + d13.x);   // d02 + i*d13
        X[i3] = make_float2(d02.x + d13.y, d02.y - d13.x);   // d02 - i*d13
    }
    __syncthreads();
}

__device__ __forceinline__ void reg_fwd(float2* E) {
    const float C = 0.70710678118654752f;
    {
        float2 t0=cadd(E[0],E[4]), t1=csub(E[0],E[4]);
        float2 t2=cadd(E[2],E[6]), t3=csub(E[2],E[6]);
        E[0]=cadd(t0,t2);
        E[4]=csub(t0,t2);
        E[2]=make_float2(t1.x+t3.y, t1.y-t3.x);
        E[6]=make_float2(t1.x-t3.y, t1.y+t3.x);
    }
    {
        float2 t0=cadd(E[1],E[5]), t1=csub(E[1],E[5]);
        float2 t2=cadd(E[3],E[7]), t3=csub(E[3],E[7]);
        float2 y0=cadd(t0,t2), y2=csub(t0,t2);
        float2 y1=make_float2(t1.x+t3.y, t1.y-t3.x);
        float2 y3=make_float2(t1.x-t3.y, t1.y+t3.x);
        E[1]=y0;
        E[3]=make_float2(C*(y1.x+y1.y),  C*(y1.y-y1.x));
        E[5]=make_float2(y2.y, -y2.x);
        E[7]=make_float2(C*(y3.y-y3.x), -C*(y3.x+y3.y));
    }
    #pragma unroll
    for (int j = 0; j < 8; j += 2) {
        float2 a=E[j], b=E[j+1];
        E[j]=cadd(a,b); E[j+1]=csub(a,b);
    }
}
__device__ __forceinline__ void reg_inv(float2* E) {
    const float C = 0.70710678118654752f;
    #pragma unroll
    for (int j = 0; j < 8; j += 2) {
        float2 a=E[j], b=E[j+1];
        E[j]=cadd(a,b); E[j+1]=csub(a,b);
    }
    {
        float2 u0=E[0], u1=E[2], u2=E[4], u3=E[6];
        float2 s02=cadd(u0,u2), d02=csub(u0,u2);
        float2 s13=cadd(u1,u3), d13=csub(u1,u3);
        E[0]=cadd(s02,s13);
        E[4]=csub(s02,s13);
        E[2]=make_float2(d02.x - d13.y, d02.y + d13.x);
        E[6]=make_float2(d02.x + d13.y, d02.y - d13.x);
    }
    {
        float2 z1=E[3], z2=E[5], z3=E[7];
        float2 u0=E[1];
        float2 u1=make_float2(C*(z1.x - z1.y), C*(z1.x + z1.y));
        float2 u2=make_float2(-z2.y, z2.x);
        float2 u3=make_float2(-C*(z3.x + z3.y), C*(z3.x - z3.y));
        float2 s02=cadd(u0,u2), d02=csub(u0,u2);
        float2 s13=cadd(u1,u3), d13=csub(u1,u3);
        E[1]=cadd(s02,s13);
        E[5]=csub(s02,s13);
        E[3]=make_float2(d02.x - d13.y, d02.y + d13.x);
        E[7]=make_float2(d02.x + d13.y, d02.y - d13.x);
    }
}

// thread t owns logical elems 8t..8t+7 == phys 9t..9t+7 (contiguous)
__device__ __forceinline__ void load8p(const float2* X, int t, float2* E) {
    const float2* b = X + 9*t;
    #pragma unroll
    for (int j = 0; j < 8; ++j) E[j] = b[j];
}
__device__ __forceinline__ void store8p(float2* X, int t, const float2* E) {
    float2* b = X + 9*t;
    #pragma unroll
    for (int j = 0; j < 8; ++j) b[j] = E[j];
}

// -------- merged 1024-thread dispatch: blocks [0,512) fft_filt, [512,4608) conv+T
__global__ __launch_bounds__(FT)
void filtconv_kernel(const float* __restrict__ filtT, float2* __restrict__ Fbr,
                     const unsigned short* __restrict__ u,
                     const float* __restrict__ conv_w, const float* __restrict__ conv_b,
                     unsigned short* __restrict__ uT) {
    __shared__ __align__(16) char fsm[XSZ * sizeof(float2)];   // 72 KB union
    const int bid = blockIdx.x;
    const int t = threadIdx.x;
    if (bid < 512) {
        float2* X = (float2*)fsm;
        const int dd = bid;
        const float* f = filtT + (size_t)dd * FFT_N;
        {
            float4 a = *(const float4*)(f + 8*t);
            float4 b = *(const float4*)(f + 8*t + 4);
            float2 E[8];
            E[0]=make_float2(a.x,0.f); E[1]=make_float2(a.y,0.f);
            E[2]=make_float2(a.z,0.f); E[3]=make_float2(a.w,0.f);
            E[4]=make_float2(b.x,0.f); E[5]=make_float2(b.y,0.f);
            E[6]=make_float2(b.z,0.f); E[7]=make_float2(b.w,0.f);
            store8p(X, t, E);
        }
        __syncthreads();
        dif4_stage<11>(X);
        dif4_stage<9>(X);
        dif4_stage<7>(X);
        dif4_stage<5>(X);
        dif4_stage<3>(X);
        {
            float2 E[8];
            load8p(X, t, E);
            reg_fwd(E);
            float2* o = Fbr + (size_t)dd*FFT_N + 8*t;
            #pragma unroll
            for (int j = 0; j < 8; ++j) o[j] = E[j];
        }
    } else {
        float (*tile)[65] = (float(*)[65])fsm;                 // [66][65] = 16.8 KB
        const int lb = bid - 512;
        const int dt = lb & 7, st = (lb >> 3) & 127, b = lb >> 10;
        const int d0 = dt*64, s0 = st*64;
        const int rr = t >> 4, c4 = (t & 15) * 4;
        for (int r = rr; r < 66; r += 64) {
            const int s = s0 + r - 1;
            float v0=0.f, v1=0.f, v2=0.f, v3=0.f;
            if (s >= 0 && s < NS) {
                short4v xv = *(const short4v*)&u[((size_t)(b*NS + s))*DIM + d0 + c4];
                v0=bf2f((unsigned short)xv[0]); v1=bf2f((unsigned short)xv[1]);
                v2=bf2f((unsigned short)xv[2]); v3=bf2f((unsigned short)xv[3]);
            }
            tile[r][c4]=v0; tile[r][c4+1]=v1; tile[r][c4+2]=v2; tile[r][c4+3]=v3;
        }
        __syncthreads();
        const int dc = t >> 4, s4 = (t & 15) * 4;
        const int d = d0 + dc;
        const float w0 = conv_w[d*3], w1 = conv_w[d*3+1], w2 = conv_w[d*3+2];
        const float cb = conv_b[d];
        short4v o;
        #pragma unroll
        for (int j = 0; j < 4; ++j) {
            const int sx = s4 + j;
            const float val = tile[sx][dc]*w0 + tile[sx+1][dc]*w1 + tile[sx+2][dc]*w2 + cb;
            o[j] = (short)f2bf(val);
        }
        *(short4v*)&uT[((size_t)(b*DIM + d))*FFT_N + s0 + s4] = o;
    }
}

// packed-pair circular conv, in-place bf16: rows (2p,d) and (2p+1,d) of uT
__global__ __launch_bounds__(FT)
void fft_conv_kernel(unsigned short* __restrict__ uT, const float2* __restrict__ Fbr) {
    __shared__ float2 X[XSZ];
    const int d = blockIdx.x & (DIM - 1);
    const int p = blockIdx.x >> 9;
    unsigned short* u1 = uT + (size_t)((2*p    )*DIM + d) * FFT_N;
    unsigned short* u2 = uT + (size_t)((2*p + 1)*DIM + d) * FFT_N;
    const int t = threadIdx.x;
    {
        short8v a = *(const short8v*)(u1 + 8*t);
        short8v b = *(const short8v*)(u2 + 8*t);
        float2 E[8];
        #pragma unroll
        for (int j = 0; j < 8; ++j)
            E[j] = make_float2(bf2f((unsigned short)a[j]), bf2f((unsigned short)b[j]));
        store8p(X, t, E);
    }
    __syncthreads();
    dif4_stage<11>(X);
    dif4_stage<9>(X);
    dif4_stage<7>(X);
    dif4_stage<5>(X);
    dif4_stage<3>(X);
    {
        float2 E[8];
        load8p(X, t, E);
        reg_fwd(E);
        const float2* F = Fbr + (size_t)d*FFT_N + 8*t;
        #pragma unroll
        for (int j = 0; j < 8; ++j) E[j] = cmulf(E[j], F[j]);
        reg_inv(E);
        store8p(X, t, E);
    }
    __syncthreads();
    dit4_stage_inv<3>(X);
    dit4_stage_inv<5>(X);
    dit4_stage_inv<7>(X);
    dit4_stage_inv<9>(X);
    dit4_stage_inv<11>(X);
    {
        float2 E[8];
        load8p(X, t, E);
        const float sc = 1.0f / (float)FFT_N;
        short8v a, b;
        #pragma unroll
        for (int j = 0; j < 8; ++j) {
            a[j] = (short)f2bf(E[j].x * sc);
            b[j] = (short)f2bf(E[j].y * sc);
        }
        *(short8v*)(u1 + 8*t) = a;
        *(short8v*)(u2 + 8*t) = b;
    }
}

// ---------------------------------------------------------------- gating
__global__ void gate_kernel(unsigned short* __restrict__ vg, const unsigned short* __restrict__ yT) {
    __shared__ float tile[64][65];
    const int bid = blockIdx.x;
    const int dt = bid & 7, st = (bid >> 3) & 127, b = bid >> 10;
    const int d0 = dt*64, s0 = st*64;
    const int t = threadIdx.x;
    const int dl = t >> 4, s4 = (t & 15) * 4;
    #pragma unroll
    for (int p = 0; p < 4; ++p) {
        const int d = dl + p*16;
        short4v y = *(const short4v*)&yT[((size_t)(b*DIM + d0 + d))*FFT_N + s0 + s4];
        tile[d][s4]  =bf2f((unsigned short)y[0]); tile[d][s4+1]=bf2f((unsigned short)y[1]);
        tile[d][s4+2]=bf2f((unsigned short)y[2]); tile[d][s4+3]=bf2f((unsigned short)y[3]);
    }
    __syncthreads();
    const int sl = t >> 4, d4 = (t & 15) * 4;
    #pragma unroll
    for (int p = 0; p < 4; ++p) {
        const int s = s0 + sl + p*16;
        unsigned short* pv = &vg[((size_t)(b*NS + s))*DIM + d0 + d4];
        short4v v = *(short4v*)pv;
        short4v o;
        #pragma unroll
        for (int j = 0; j < 4; ++j)
            o[j] = (short)f2bf(bf2f((unsigned short)v[j]) * tile[d4+j][sl + p*16]);
        *(short4v*)pv = o;
    }
}

// ---------------------------------------------------------------- bf16 GEMM
// Double-buffered pipeline + XCD swizzle. Grid dim3(4, 256).
// MODE 0: Cb = bf16(val);  MODE 2: Cf = val (fp32)
template<int MODE>
__global__ __launch_bounds__(256)
void gemm_bt_kernel(const unsigned short* __restrict__ A,
                    const unsigned short* __restrict__ BT,
                    const float* __restrict__ bias,
                    float* __restrict__ Cf,
                    unsigned short* __restrict__ Cb) {
    __shared__ unsigned short As[2][4096];
    __shared__ unsigned short Bs[2][4096];
    const int tid = threadIdx.x;
    const int wid = tid >> 6, lane = tid & 63;
    const int bid = blockIdx.y * 4 + blockIdx.x;
    const int swz = (bid & 7) * 128 + (bid >> 3);
    const int m0 = (swz >> 2) * 128, n0 = (swz & 3) * 128;
    const int srow = wid*16 + (lane >> 2);
    const int scol = (lane & 3) * 8;
    const unsigned short* gA = A  + (size_t)(m0 + srow)*DIM + scol;
    const unsigned short* gB = BT + (size_t)(n0 + srow)*DIM + scol;
    const int wr = wid >> 1, wc = wid & 1;
    const int fr = lane & 15, fq = lane >> 4;
    f32x4 acc[4][4] = {};
    gload16(gA,                  &As[0][wid*512]);
    gload16(gA + (size_t)64*DIM, &As[0][wid*512 + 2048]);
    gload16(gB,                  &Bs[0][wid*512]);
    gload16(gB + (size_t)64*DIM, &Bs[0][wid*512 + 2048]);
    int cur = 0;
    for (int k0 = 0; k0 < DIM; k0 += 32) {
        __syncthreads();
        if (k0 + 32 < DIM) {
            const int nx = cur ^ 1;
            gload16(gA + k0 + 32,                  &As[nx][wid*512]);
            gload16(gA + k0 + 32 + (size_t)64*DIM, &As[nx][wid*512 + 2048]);
            gload16(gB + k0 + 32,                  &Bs[nx][wid*512]);
            gload16(gB + k0 + 32 + (size_t)64*DIM, &Bs[nx][wid*512 + 2048]);
        }
        bf16x8 af[4], bfr[4];
        #pragma unroll
        for (int mi = 0; mi < 4; ++mi)
            af[mi] = *(const bf16x8*)&As[cur][(wr*64 + mi*16 + fr)*32 + fq*8];
        #pragma unroll
        for (int ni = 0; ni < 4; ++ni)
            bfr[ni] = *(const bf16x8*)&Bs[cur][(wc*64 + ni*16 + fr)*32 + fq*8];
        #pragma unroll
        for (int mi = 0; mi < 4; ++mi)
            #pragma unroll
            for (int ni = 0; ni < 4; ++ni)
                acc[mi][ni] = __builtin_amdgcn_mfma_f32_16x16x32_bf16(af[mi], bfr[ni], acc[mi][ni], 0, 0, 0);
        cur ^= 1;
    }
    #pragma unroll
    for (int ni = 0; ni < 4; ++ni) {
        const int c = n0 + wc*64 + ni*16 + fr;
        const float bv = bias[c];
        #pragma unroll
        for (int mi = 0; mi < 4; ++mi) {
            const int rbase = m0 + wr*64 + mi*16 + fq*4;
            #pragma unroll
            for (int j = 0; j < 4; ++j) {
                const size_t idx = (size_t)(rbase + j)*DIM + c;
                const float val = acc[mi][ni][j] + bv;
                if (MODE == 0) Cb[idx] = f2bf(val);
                else           Cf[idx] = val;
            }
        }
    }
}

// ------- merged dispatch, grid dim3(4, 768):
//   blocks [0,1024)    -> g0 = (v+bv)*sigmoid(z+bz)   (2 acc sets)
//   blocks [1024,2048) -> u = x@Wu+bu                 (1 acc set)
//   blocks [2048,3072) -> transpose filt (NS,DIM) -> filtT (DIM,NS)
// LDS union 48KB, block-uniform branch. filt/filtT disjoint from W2/W3.
__global__ __launch_bounds__(256)
void gemm_vzu2t_kernel(const unsigned short* __restrict__ A,
                       const unsigned short* __restrict__ BT,   // w_inT (1536,512)
                       const float* __restrict__ bias,          // b_in (1536)
                       unsigned short* __restrict__ Gb,         // g0 (B,S,D)
                       unsigned short* __restrict__ Ub,         // u  (B,S,D)
                       const float* __restrict__ filt,          // (NS, DIM)
                       float* __restrict__ filtT) {             // (DIM, NS)
    __shared__ __align__(16) char gsm[49152];
    unsigned short (*As)[4096] = (unsigned short(*)[4096])(gsm);
    unsigned short (*B1)[4096] = (unsigned short(*)[4096])(gsm + 16384);
    unsigned short (*B2)[4096] = (unsigned short(*)[4096])(gsm + 32768);
    const int tid = threadIdx.x;
    const int wid = tid >> 6, lane = tid & 63;
    const int bid = blockIdx.y * 4 + blockIdx.x;

    if (bid >= 2048) {                       // ---- filt transpose range (1024 blocks)
        float (*tile)[65] = (float(*)[65])gsm;
        const int li = bid - 2048;
        const int c0 = (li & 7) * 64, r0 = (li >> 3) * 64;   // c over DIM (8), r over NS (128)
        const int rr = tid >> 4, c4 = (tid & 15) * 4;
        #pragma unroll
        for (int p = 0; p < 4; ++p) {
            const int r = rr + p*16;
            float4 v = *(const float4*)&filt[(size_t)(r0 + r)*DIM + c0 + c4];
            tile[r][c4+0]=v.x; tile[r][c4+1]=v.y; tile[r][c4+2]=v.z; tile[r][c4+3]=v.w;
        }
        __syncthreads();
        const int cc = tid >> 4, r4 = (tid & 15) * 4;
        #pragma unroll
        for (int p = 0; p < 4; ++p) {
            const int c = cc + p*16;
            float4 o = make_float4(tile[r4+0][c], tile[r4+1][c], tile[r4+2][c], tile[r4+3][c]);
            *(float4*)&filtT[(size_t)(c0 + c)*NS + r0 + r4] = o;
        }
        return;
    }

    const bool is_u = bid >= 1024;
    const int lbid = bid & 1023;
    const int swz = (lbid & 7) * 128 + (lbid >> 3);
    const int m0 = (swz >> 2) * 128, n0 = (swz & 3) * 128;
    const int srow = wid*16 + (lane >> 2);
    const int scol = (lane & 3) * 8;
    const unsigned short* gA = A + (size_t)(m0 + srow)*DIM + scol;
    const int wr = wid >> 1, wc = wid & 1;
    const int fr = lane & 15, fq = lane >> 4;

    if (!is_u) {
        const unsigned short* gBv = BT + (size_t)(n0 + srow)*DIM + scol;
        const unsigned short* gBz = BT + (size_t)(1024 + n0 + srow)*DIM + scol;
        f32x4 accv[4][4] = {};
        f32x4 accz[4][4] = {};
        gload16(gA,                   &As[0][wid*512]);
        gload16(gA  + (size_t)64*DIM, &As[0][wid*512 + 2048]);
        gload16(gBv,                  &B1[0][wid*512]);
        gload16(gBv + (size_t)64*DIM, &B1[0][wid*512 + 2048]);
        gload16(gBz,                  &B2[0][wid*512]);
        gload16(gBz + (size_t)64*DIM, &B2[0][wid*512 + 2048]);
        int cur = 0;
        for (int k0 = 0; k0 < DIM; k0 += 32) {
            __syncthreads();
            if (k0 + 32 < DIM) {
                const int nx = cur ^ 1;
                gload16(gA  + k0 + 32,                  &As[nx][wid*512]);
                gload16(gA  + k0 + 32 + (size_t)64*DIM, &As[nx][wid*512 + 2048]);
                gload16(gBv + k0 + 32,                  &B1[nx][wid*512]);
                gload16(gBv + k0 + 32 + (size_t)64*DIM, &B1[nx][wid*512 + 2048]);
                gload16(gBz + k0 + 32,                  &B2[nx][wid*512]);
                gload16(gBz + k0 + 32 + (size_t)64*DIM, &B2[nx][wid*512 + 2048]);
            }
            bf16x8 af[4], bf_[4];
            #pragma unroll
            for (int mi = 0; mi < 4; ++mi)
                af[mi] = *(const bf16x8*)&As[cur][(wr*64 + mi*16 + fr)*32 + fq*8];
            #pragma unroll
            for (int ni = 0; ni < 4; ++ni)
                bf_[ni] = *(const bf16x8*)&B1[cur][(wc*64 + ni*16 + fr)*32 + fq*8];
            #pragma unroll
            for (int mi = 0; mi < 4; ++mi)
                #pragma unroll
                for (int ni = 0; ni < 4; ++ni)
                    accv[mi][ni] = __builtin_amdgcn_mfma_f32_16x16x32_bf16(af[mi], bf_[ni], accv[mi][ni], 0, 0, 0);
            #pragma unroll
            for (int ni = 0; ni < 4; ++ni)
                bf_[ni] = *(const bf16x8*)&B2[cur][(wc*64 + ni*16 + fr)*32 + fq*8];
            #pragma unroll
            for (int mi = 0; mi < 4; ++mi)
                #pragma unroll
                for (int ni = 0; ni < 4; ++ni)
                    accz[mi][ni] = __builtin_amdgcn_mfma_f32_16x16x32_bf16(af[mi], bf_[ni], accz[mi][ni], 0, 0, 0);
            cur ^= 1;
        }
        #pragma unroll
        for (int ni = 0; ni < 4; ++ni) {
            const int c = n0 + wc*64 + ni*16 + fr;
            const float bv = bias[c];
            const float bz = bias[1024 + c];
            #pragma unroll
            for (int mi = 0; mi < 4; ++mi) {
                const int rbase = m0 + wr*64 + mi*16 + fq*4;
                #pragma unroll
                for (int j = 0; j < 4; ++j) {
                    const size_t idx = (size_t)(rbase + j)*DIM + c;
                    const float vv = accv[mi][ni][j] + bv;
                    const float zz = accz[mi][ni][j] + bz;
                    const float sg = 1.0f / (1.0f + __expf(-zz));
                    Gb[idx] = f2bf(vv * sg);
                }
            }
        }
    } else {
        const unsigned short* gBu = BT + (size_t)(512 + n0 + srow)*DIM + scol;
        f32x4 acc[4][4] = {};
        gload16(gA,                   &As[0][wid*512]);
        gload16(gA  + (size_t)64*DIM, &As[0][wid*512 + 2048]);
        gload16(gBu,                  &B1[0][wid*512]);
        gload16(gBu + (size_t)64*DIM, &B1[0][wid*512 + 2048]);
        int cur = 0;
        for (int k0 = 0; k0 < DIM; k0 += 32) {
            __syncthreads();
            if (k0 + 32 < DIM) {
                const int nx = cur ^ 1;
                gload16(gA  + k0 + 32,                  &As[nx][wid*512]);
                gload16(gA  + k0 + 32 + (size_t)64*DIM, &As[nx][wid*512 + 2048]);
                gload16(gBu + k0 + 32,                  &B1[nx][wid*512]);
                gload16(gBu + k0 + 32 + (size_t)64*DIM, &B1[nx][wid*512 + 2048]);
            }
            bf16x8 af[4], bf_[4];
            #pragma unroll
            for (int mi = 0; mi < 4; ++mi)
                af[mi] = *(const bf16x8*)&As[cur][(wr*64 + mi*16 + fr)*32 + fq*8];
            #pragma unroll
            for (int ni = 0; ni < 4; ++ni)
                bf_[ni] = *(const bf16x8*)&B1[cur][(wc*64 + ni*16 + fr)*32 + fq*8];
            #pragma unroll
            for (int mi = 0; mi < 4; ++mi)
                #pragma unroll
                for (int ni = 0; ni < 4; ++ni)
                    acc[mi][ni] = __builtin_amdgcn_mfma_f32_16x16x32_bf16(af[mi], bf_[ni], acc[mi][ni], 0, 0, 0);
            cur ^= 1;
        }
        #pragma unroll
        for (int ni = 0; ni < 4; ++ni) {
            const int c = n0 + wc*64 + ni*16 + fr;
            const float bu = bias[512 + c];
            #pragma unroll
            for (int mi = 0; mi < 4; ++mi) {
                const int rbase = m0 + wr*64 + mi*16 + fq*4;
                #pragma unroll
                for (int j = 0; j < 4; ++j) {
                    const size_t idx = (size_t)(rbase + j)*DIM + c;
                    Ub[idx] = f2bf(acc[mi][ni][j] + bu);
                }
            }
        }
    }
}

// ---------------------------------------------------------------- launcher
extern "C" void kernel_launch(void* const* d_in, const int* in_sizes, int n_in,
                              void* d_out, int out_size, void* d_ws, size_t ws_size,
                              hipStream_t stream) {
    const float* x      = (const float*)d_in[0];
    const float* w1     = (const float*)d_in[1];
    const float* b1     = (const float*)d_in[2];
    const float* w2     = (const float*)d_in[3];
    const float* b2     = (const float*)d_in[4];
    const float* w3     = (const float*)d_in[5];
    const float* b3     = (const float*)d_in[6];
    const float* conv_w = (const float*)d_in[7];
    const float* conv_b = (const float*)d_in[8];
    const float* w_in   = (const float*)d_in[9];
    const float* b_in   = (const float*)d_in[10];
    const float* w_out  = (const float*)d_in[11];
    const float* b_out  = (const float*)d_in[12];
    float* out = (float*)d_out;

    const size_t NEED = 167772160ULL;              // 160 MiB (known to fit)
    if (ws_size < NEED) return;
    char* ws = (char*)d_ws;
    float2*         Fbr    = (float2*)ws;                               // [0,32M)  (filt dead by then)
    float*          filt   = (float*)ws;                                // [0,16M)  temp
    unsigned short* xb     = (unsigned short*)(ws + (size_t)( 32<<20)); // [32,64M) x bf16 -> uT
    unsigned short* W2     = (unsigned short*)(ws + (size_t)( 64<<20)); // [64,96M) g0/g
    unsigned short* W3     = (unsigned short*)(ws + (size_t)( 96<<20)); // [96,128M) u (B,S,D)
    char*           W4     = ws + (size_t)(128<<20);                    // [128,160M)
    unsigned short* w_inT  = (unsigned short*)W4;                       // +0, 1.5 MiB
    unsigned short* w_outT = (unsigned short*)(W4 + (size_t)(2<<20));   // +2M, 0.5 MiB
    float*          filtT  = (float*)(W4 + (size_t)(4<<20));            // +4M, 16 MiB (private)

    // 1. mega prep: cast x -> xb, cast+T weights, filter MLP -> filt (S,D)@[0,16M)
    mega_prep_kernel<<<10496, 256, 0, stream>>>(x, xb, w_in, w_inT, w_out, w_outT,
                                                w1, b1, w2, b2, w3, b3, filt);
    // 2. merged: g0 -> W2, u -> W3, filt transpose -> filtT (disjoint buffers)
    gemm_vzu2t_kernel<<<dim3(4, 768), 256, 0, stream>>>(xb, w_inT, b_in, W2, W3, filt, filtT);
    // 3. merged: filter spectrum filtT -> Fbr (overwrites filt; consumed) | conv W3 -> xb
    filtconv_kernel<<<4608, FT, 0, stream>>>(filtT, Fbr, W3, conv_w, conv_b, xb);
    // 4. packed FFT circular conv, in-place on xb rows
    fft_conv_kernel<<<(NB/2)*DIM, FT, 0, stream>>>(xb, Fbr);
    // 5. g = g0 * y (transposed read of xb), in-place on W2
    gate_kernel<<<NB*(NS/64)*(DIM/64), 256, 0, stream>>>(W2, xb);
    // 6. out = g @ w_out + b_out -> d_out fp32
    gemm_bt_kernel<2><<<dim3(4, MTOT/128), 256, 0, stream>>>(W2, w_outT, b_out, out, nullptr);
}

// Round 17
// 247.040 us; speedup vs baseline: 1.7519x; 1.0421x over previous
//
#include <hip/hip_runtime.h>
#include <math.h>

#define DIM   512
#define NB    4
#define NS    8192
#define FFT_N 8192
#define FT    1024
#define MTOT  (NB*NS)

// padded LDS index map for FFT stages
#define IDX(i) ((i) + ((i) >> 3))
#define XSZ   9216

typedef __attribute__((ext_vector_type(8))) short bf16x8;
typedef __attribute__((ext_vector_type(4))) short short4v;
typedef __attribute__((ext_vector_type(8))) short short8v;
typedef __attribute__((ext_vector_type(4))) float f32x4;

// ---------------------------------------------------------------- helpers
__device__ __forceinline__ float bf2f(unsigned short u) {
    union { unsigned int i; float f; } v; v.i = ((unsigned int)u) << 16; return v.f;
}
__device__ __forceinline__ unsigned short f2bf(float f) {
    union { float f; unsigned int i; } v; v.f = f;
    unsigned int r = v.i + 0x7fffu + ((v.i >> 16) & 1u);
    return (unsigned short)(r >> 16);
}
__device__ __forceinline__ float2 cmulf(float2 a, float2 b) {
    return make_float2(a.x*b.x - a.y*b.y, a.x*b.y + a.y*b.x);
}
__device__ __forceinline__ float2 cadd(float2 a, float2 b) { return make_float2(a.x+b.x, a.y+b.y); }
__device__ __forceinline__ float2 csub(float2 a, float2 b) { return make_float2(a.x-b.x, a.y-b.y); }
__device__ __forceinline__ float gelu_exact(float x) {
    return 0.5f * x * (1.0f + erff(x * 0.70710678118654752f));
}
__device__ __forceinline__ void gload16(const void* g, void* l) {
    __builtin_amdgcn_global_load_lds((const __attribute__((address_space(1))) void*)g,
                                     (__attribute__((address_space(3))) void*)l, 16, 0, 0);
}

// ---------------- mega prep: cast_x | castT(w_in) | castT(w_out) | filter MLP
__device__ __forceinline__ void castT_body(const float* __restrict__ in,
                                           unsigned short* __restrict__ outT,
                                           int R, int C, int bx, int by, int t,
                                           float tile[64][65]) {
    const int c0 = bx * 64, r0 = by * 64;
    const int rr = t >> 4, c4 = (t & 15) * 4;
    #pragma unroll
    for (int p = 0; p < 4; ++p) {
        const int r = rr + p*16;
        float4 v = *(const float4*)&in[(size_t)(r0 + r)*C + c0 + c4];
        tile[r][c4+0]=v.x; tile[r][c4+1]=v.y; tile[r][c4+2]=v.z; tile[r][c4+3]=v.w;
    }
    __syncthreads();
    const int cc = t >> 4, r4 = (t & 15) * 4;
    #pragma unroll
    for (int p = 0; p < 4; ++p) {
        const int c = cc + p*16;
        short4v o;
        o[0] = (short)f2bf(tile[r4+0][c]); o[1] = (short)f2bf(tile[r4+1][c]);
        o[2] = (short)f2bf(tile[r4+2][c]); o[3] = (short)f2bf(tile[r4+3][c]);
        *(short4v*)&outT[(size_t)(c0 + c)*R + r0 + r4] = o;
    }
}

__global__ void mega_prep_kernel(const float* __restrict__ x, unsigned short* __restrict__ xb,
                                 const float* __restrict__ w_in, unsigned short* __restrict__ w_inT,
                                 const float* __restrict__ w_out, unsigned short* __restrict__ w_outT,
                                 const float* __restrict__ w1, const float* __restrict__ b1,
                                 const float* __restrict__ w2, const float* __restrict__ b2,
                                 const float* __restrict__ w3, const float* __restrict__ b3,
                                 float* __restrict__ filt) {
    __shared__ float tile[64][65];
    __shared__ float h1s[4][64];
    __shared__ float h2s[4][64];
    const int bid = blockIdx.x;
    const int t = threadIdx.x;
    if (bid < 8192) {
        const size_t i = ((size_t)bid * 256 + t) * 8;
        float4 a = *(const float4*)&x[i];
        float4 b = *(const float4*)&x[i+4];
        short8v o;
        o[0]=(short)f2bf(a.x); o[1]=(short)f2bf(a.y); o[2]=(short)f2bf(a.z); o[3]=(short)f2bf(a.w);
        o[4]=(short)f2bf(b.x); o[5]=(short)f2bf(b.y); o[6]=(short)f2bf(b.z); o[7]=(short)f2bf(b.w);
        *(short8v*)&xb[i] = o;
    } else if (bid < 8384) {
        const int li = bid - 8192;
        castT_body(w_in, w_inT, DIM, 1536, li % 24, li / 24, t, tile);
    } else if (bid < 8448) {
        const int li = bid - 8384;
        castT_body(w_out, w_outT, DIM, DIM, li % 8, li / 8, t, tile);
    } else {
        const int sub = t >> 6, lane = t & 63;
        const int s = (bid - 8448) * 4 + sub;
        const float pos = (float)s / (float)(NS - 1);
        h1s[sub][lane] = gelu_exact(pos * w1[lane] + b1[lane]);
        __syncthreads();
        float acc = b2[lane];
        #pragma unroll 8
        for (int j = 0; j < 64; ++j) acc += h1s[sub][j] * w2[j*64 + lane];
        h2s[sub][lane] = gelu_exact(acc);
        __syncthreads();
        for (int d = lane; d < DIM; d += 64) {
            float o = b3[d];
            #pragma unroll 8
            for (int j = 0; j < 64; ++j) o += h2s[sub][j] * w3[j*DIM + d];
            filt[(size_t)s*DIM + d] = o;
        }
    }
}

// ---------------------------------------------------------------- FFT pieces
template<int LOGQ>
__device__ __forceinline__ void dif4_stage(float2* X) {
    const int q = 1 << LOGQ;
    const float step = -6.28318530717958647692f / (float)(4*q);
    #pragma unroll
    for (int it = 0; it < (FFT_N/4)/FT; ++it) {
        const int idx = threadIdx.x + it*FT;
        const int g = idx >> LOGQ, k = idx & (q-1);
        const int base = (g << (LOGQ+2)) + k;
        const int i0 = IDX(base), i1 = IDX(base+q), i2 = IDX(base+2*q), i3 = IDX(base+3*q);
        float2 a=X[i0], b=X[i1], c=X[i2], d=X[i3];
        float2 t0=cadd(a,c), t1=csub(a,c), t2=cadd(b,d), t3=csub(b,d);
        float2 y0=cadd(t0,t2), y2=csub(t0,t2);
        float2 y1=make_float2(t1.x+t3.y, t1.y-t3.x);
        float2 y3=make_float2(t1.x-t3.y, t1.y+t3.x);
        float sv, cv; __sincosf(step*(float)k, &sv, &cv);
        float2 w1=make_float2(cv, sv);
        float2 w2=cmulf(w1, w1);
        float2 w3=cmulf(w2, w1);
        X[i0] = y0;
        X[i1] = cmulf(y1, w1);
        X[i2] = cmulf(y2, w2);
        X[i3] = cmulf(y3, w3);
    }
    __syncthreads();
}

template<int LOGQ>
__device__ __forceinline__ void dit4_stage_inv(float2* X) {
    const int q = 1 << LOGQ;
    const float step = 6.28318530717958647692f / (float)(4*q);
    #pragma unroll
    for (int it = 0; it < (FFT_N/4)/FT; ++it) {
        const int idx = threadIdx.x + it*FT;
        const int g = idx >> LOGQ, k = idx & (q-1);
        const int base = (g << (LOGQ+2)) + k;
        const int i0 = IDX(base), i1 = IDX(base+q), i2 = IDX(base+2*q), i3 = IDX(base+3*q);
        float sv, cv; __sincosf(step*(float)k, &sv, &cv);
        float2 w1=make_float2(cv, sv);
        float2 w2=cmulf(w1, w1);
        float2 w3=cmulf(w2, w1);
        float2 u0=X[i0];
        float2 u1=cmulf(X[i1], w1);
        float2 u2=cmulf(X[i2], w2);
        float2 u3=cmulf(X[i3], w3);
        float2 s02=cadd(u0,u2), d02=csub(u0,u2);
        float2 s13=cadd(u1,u3), d13=csub(u1,u3);
        X[i0] = cadd(s02, s13);
        X[i2] = csub(s02, s13);
        X[i1] = make_float2(d02.x - d13.y, d02.y + d13.x);
        X[i3] = make_float2(d02.x + d13.y, d02.y - d13.x);
    }
    __syncthreads();
}

__device__ __forceinline__ void reg_fwd(float2* E) {
    const float C = 0.70710678118654752f;
    {
        float2 t0=cadd(E[0],E[4]), t1=csub(E[0],E[4]);
        float2 t2=cadd(E[2],E[6]), t3=csub(E[2],E[6]);
        E[0]=cadd(t0,t2);
        E[4]=csub(t0,t2);
        E[2]=make_float2(t1.x+t3.y, t1.y-t3.x);
        E[6]=make_float2(t1.x-t3.y, t1.y+t3.x);
    }
    {
        float2 t0=cadd(E[1],E[5]), t1=csub(E[1],E[5]);
        float2 t2=cadd(E[3],E[7]), t3=csub(E[3],E[7]);
        float2 y0=cadd(t0,t2), y2=csub(t0,t2);
        float2 y1=make_float2(t1.x+t3.y, t1.y-t3.x);
        float2 y3=make_float2(t1.x-t3.y, t1.y+t3.x);
        E[1]=y0;
        E[3]=make_float2(C*(y1.x+y1.y),  C*(y1.y-y1.x));
        E[5]=make_float2(y2.y, -y2.x);
        E[7]=make_float2(C*(y3.y-y3.x), -C*(y3.x+y3.y));
    }
    #pragma unroll
    for (int j = 0; j < 8; j += 2) {
        float2 a=E[j], b=E[j+1];
        E[j]=cadd(a,b); E[j+1]=csub(a,b);
    }
}
__device__ __forceinline__ void reg_inv(float2* E) {
    const float C = 0.70710678118654752f;
    #pragma unroll
    for (int j = 0; j < 8; j += 2) {
        float2 a=E[j], b=E[j+1];
        E[j]=cadd(a,b); E[j+1]=csub(a,b);
    }
    {
        float2 u0=E[0], u1=E[2], u2=E[4], u3=E[6];
        float2 s02=cadd(u0,u2), d02=csub(u0,u2);
        float2 s13=cadd(u1,u3), d13=csub(u1,u3);
        E[0]=cadd(s02,s13);
        E[4]=csub(s02,s13);
        E[2]=make_float2(d02.x - d13.y, d02.y + d13.x);
        E[6]=make_float2(d02.x + d13.y, d02.y - d13.x);
    }
    {
        float2 z1=E[3], z2=E[5], z3=E[7];
        float2 u0=E[1];
        float2 u1=make_float2(C*(z1.x - z1.y), C*(z1.x + z1.y));
        float2 u2=make_float2(-z2.y, z2.x);
        float2 u3=make_float2(-C*(z3.x + z3.y), C*(z3.x - z3.y));
        float2 s02=cadd(u0,u2), d02=csub(u0,u2);
        float2 s13=cadd(u1,u3), d13=csub(u1,u3);
        E[1]=cadd(s02,s13);
        E[5]=csub(s02,s13);
        E[3]=make_float2(d02.x - d13.y, d02.y + d13.x);
        E[7]=make_float2(d02.x + d13.y, d02.y - d13.x);
    }
}

__device__ __forceinline__ void load8p(const float2* X, int t, float2* E) {
    const float2* b = X + 9*t;
    #pragma unroll
    for (int j = 0; j < 8; ++j) E[j] = b[j];
}
__device__ __forceinline__ void store8p(float2* X, int t, const float2* E) {
    float2* b = X + 9*t;
    #pragma unroll
    for (int j = 0; j < 8; ++j) b[j] = E[j];
}

// ---------------------------------------- filter spectrum (permuted order)
__global__ __launch_bounds__(FT)
void fft_filt_kernel(const float* __restrict__ filtT, float2* __restrict__ Fbr) {
    __shared__ float2 X[XSZ];
    const int dd = blockIdx.x;
    const int t = threadIdx.x;
    const float* f = filtT + (size_t)dd * FFT_N;
    {
        float4 a = *(const float4*)(f + 8*t);
        float4 b = *(const float4*)(f + 8*t + 4);
        float2 E[8];
        E[0]=make_float2(a.x,0.f); E[1]=make_float2(a.y,0.f);
        E[2]=make_float2(a.z,0.f); E[3]=make_float2(a.w,0.f);
        E[4]=make_float2(b.x,0.f); E[5]=make_float2(b.y,0.f);
        E[6]=make_float2(b.z,0.f); E[7]=make_float2(b.w,0.f);
        store8p(X, t, E);
    }
    __syncthreads();
    dif4_stage<11>(X);
    dif4_stage<9>(X);
    dif4_stage<7>(X);
    dif4_stage<5>(X);
    dif4_stage<3>(X);
    {
        float2 E[8];
        load8p(X, t, E);
        reg_fwd(E);
        float2* o = Fbr + (size_t)dd*FFT_N + 8*t;
        #pragma unroll
        for (int j = 0; j < 8; ++j) o[j] = E[j];
    }
}

// -------- packed-pair conv+FFT: rows (2p,d),(2p+1,d) of uT (pre-conv u^T).
// inline depthwise k=3 zero-pad conv on load, then circular FFT conv, in-place.
__global__ __launch_bounds__(FT)
void fft_conv_kernel(unsigned short* __restrict__ uT, const float2* __restrict__ Fbr,
                     const float* __restrict__ conv_w, const float* __restrict__ conv_b) {
    __shared__ float2 X[XSZ];
    const int d = blockIdx.x & (DIM - 1);
    const int p = blockIdx.x >> 9;
    unsigned short* u1 = uT + (size_t)((2*p    )*DIM + d) * FFT_N;
    unsigned short* u2 = uT + (size_t)((2*p + 1)*DIM + d) * FFT_N;
    const int t = threadIdx.x;
    {
        short8v a = *(const short8v*)(u1 + 8*t);
        short8v b = *(const short8v*)(u2 + 8*t);
        const float al = (t == 0)    ? 0.f : bf2f(u1[8*t - 1]);
        const float ar = (t == FT-1) ? 0.f : bf2f(u1[8*t + 8]);
        const float bl = (t == 0)    ? 0.f : bf2f(u2[8*t - 1]);
        const float br = (t == FT-1) ? 0.f : bf2f(u2[8*t + 8]);
        const float w0 = conv_w[d*3], w1 = conv_w[d*3+1], w2c = conv_w[d*3+2];
        const float cb = conv_b[d];
        float xa[10], xb[10];
        xa[0] = al; xb[0] = bl;
        #pragma unroll
        for (int j = 0; j < 8; ++j) {
            xa[j+1] = bf2f((unsigned short)a[j]);
            xb[j+1] = bf2f((unsigned short)b[j]);
        }
        xa[9] = ar; xb[9] = br;
        float2 E[8];
        #pragma unroll
        for (int j = 0; j < 8; ++j)
            E[j] = make_float2(w0*xa[j] + w1*xa[j+1] + w2c*xa[j+2] + cb,
                               w0*xb[j] + w1*xb[j+1] + w2c*xb[j+2] + cb);
        store8p(X, t, E);
    }
    __syncthreads();
    dif4_stage<11>(X);
    dif4_stage<9>(X);
    dif4_stage<7>(X);
    dif4_stage<5>(X);
    dif4_stage<3>(X);
    {
        float2 E[8];
        load8p(X, t, E);
        reg_fwd(E);
        const float2* F = Fbr + (size_t)d*FFT_N + 8*t;
        #pragma unroll
        for (int j = 0; j < 8; ++j) E[j] = cmulf(E[j], F[j]);
        reg_inv(E);
        store8p(X, t, E);
    }
    __syncthreads();
    dit4_stage_inv<3>(X);
    dit4_stage_inv<5>(X);
    dit4_stage_inv<7>(X);
    dit4_stage_inv<9>(X);
    dit4_stage_inv<11>(X);
    {
        float2 E[8];
        load8p(X, t, E);
        const float sc = 1.0f / (float)FFT_N;
        short8v a, b;
        #pragma unroll
        for (int j = 0; j < 8; ++j) {
            a[j] = (short)f2bf(E[j].x * sc);
            b[j] = (short)f2bf(E[j].y * sc);
        }
        *(short8v*)(u1 + 8*t) = a;
        *(short8v*)(u2 + 8*t) = b;
    }
}

// ---------------------------------------------------------------- gating
__global__ void gate_kernel(unsigned short* __restrict__ vg, const unsigned short* __restrict__ yT) {
    __shared__ float tile[64][65];
    const int bid = blockIdx.x;
    const int dt = bid & 7, st = (bid >> 3) & 127, b = bid >> 10;
    const int d0 = dt*64, s0 = st*64;
    const int t = threadIdx.x;
    const int dl = t >> 4, s4 = (t & 15) * 4;
    #pragma unroll
    for (int p = 0; p < 4; ++p) {
        const int d = dl + p*16;
        short4v y = *(const short4v*)&yT[((size_t)(b*DIM + d0 + d))*FFT_N + s0 + s4];
        tile[d][s4]  =bf2f((unsigned short)y[0]); tile[d][s4+1]=bf2f((unsigned short)y[1]);
        tile[d][s4+2]=bf2f((unsigned short)y[2]); tile[d][s4+3]=bf2f((unsigned short)y[3]);
    }
    __syncthreads();
    const int sl = t >> 4, d4 = (t & 15) * 4;
    #pragma unroll
    for (int p = 0; p < 4; ++p) {
        const int s = s0 + sl + p*16;
        unsigned short* pv = &vg[((size_t)(b*NS + s))*DIM + d0 + d4];
        short4v v = *(short4v*)pv;
        short4v o;
        #pragma unroll
        for (int j = 0; j < 4; ++j)
            o[j] = (short)f2bf(bf2f((unsigned short)v[j]) * tile[d4+j][sl + p*16]);
        *(short4v*)pv = o;
    }
}

// ---------------------------------------------------------------- bf16 GEMM
// MODE 0: Cb = bf16(val);  MODE 2: Cf = val (fp32)
template<int MODE>
__global__ __launch_bounds__(256)
void gemm_bt_kernel(const unsigned short* __restrict__ A,
                    const unsigned short* __restrict__ BT,
                    const float* __restrict__ bias,
                    float* __restrict__ Cf,
                    unsigned short* __restrict__ Cb) {
    __shared__ unsigned short As[2][4096];
    __shared__ unsigned short Bs[2][4096];
    const int tid = threadIdx.x;
    const int wid = tid >> 6, lane = tid & 63;
    const int bid = blockIdx.y * 4 + blockIdx.x;
    const int swz = (bid & 7) * 128 + (bid >> 3);
    const int m0 = (swz >> 2) * 128, n0 = (swz & 3) * 128;
    const int srow = wid*16 + (lane >> 2);
    const int scol = (lane & 3) * 8;
    const unsigned short* gA = A  + (size_t)(m0 + srow)*DIM + scol;
    const unsigned short* gB = BT + (size_t)(n0 + srow)*DIM + scol;
    const int wr = wid >> 1, wc = wid & 1;
    const int fr = lane & 15, fq = lane >> 4;
    f32x4 acc[4][4] = {};
    gload16(gA,                  &As[0][wid*512]);
    gload16(gA + (size_t)64*DIM, &As[0][wid*512 + 2048]);
    gload16(gB,                  &Bs[0][wid*512]);
    gload16(gB + (size_t)64*DIM, &Bs[0][wid*512 + 2048]);
    int cur = 0;
    for (int k0 = 0; k0 < DIM; k0 += 32) {
        __syncthreads();
        if (k0 + 32 < DIM) {
            const int nx = cur ^ 1;
            gload16(gA + k0 + 32,                  &As[nx][wid*512]);
            gload16(gA + k0 + 32 + (size_t)64*DIM, &As[nx][wid*512 + 2048]);
            gload16(gB + k0 + 32,                  &Bs[nx][wid*512]);
            gload16(gB + k0 + 32 + (size_t)64*DIM, &Bs[nx][wid*512 + 2048]);
        }
        bf16x8 af[4], bfr[4];
        #pragma unroll
        for (int mi = 0; mi < 4; ++mi)
            af[mi] = *(const bf16x8*)&As[cur][(wr*64 + mi*16 + fr)*32 + fq*8];
        #pragma unroll
        for (int ni = 0; ni < 4; ++ni)
            bfr[ni] = *(const bf16x8*)&Bs[cur][(wc*64 + ni*16 + fr)*32 + fq*8];
        #pragma unroll
        for (int mi = 0; mi < 4; ++mi)
            #pragma unroll
            for (int ni = 0; ni < 4; ++ni)
                acc[mi][ni] = __builtin_amdgcn_mfma_f32_16x16x32_bf16(af[mi], bfr[ni], acc[mi][ni], 0, 0, 0);
        cur ^= 1;
    }
    #pragma unroll
    for (int ni = 0; ni < 4; ++ni) {
        const int c = n0 + wc*64 + ni*16 + fr;
        const float bv = bias[c];
        #pragma unroll
        for (int mi = 0; mi < 4; ++mi) {
            const int rbase = m0 + wr*64 + mi*16 + fq*4;
            #pragma unroll
            for (int j = 0; j < 4; ++j) {
                const size_t idx = (size_t)(rbase + j)*DIM + c;
                const float val = acc[mi][ni][j] + bv;
                if (MODE == 0) Cb[idx] = f2bf(val);
                else           Cf[idx] = val;
            }
        }
    }
}

// ------- merged dispatch, grid dim3(4, 768):
//   [0,1024)    g0 = (v+bv)*sigmoid(z+bz) -> Gb (B,S,D)
//   [1024,2048) u = x@Wu+bu -> UbT (B,D,S) via epilogue LDS transpose
//   [2048,3072) transpose filt (NS,DIM) -> filtT (DIM,NS)
__global__ __launch_bounds__(256)
void gemm_vzu2t_kernel(const unsigned short* __restrict__ A,
                       const unsigned short* __restrict__ BT,
                       const float* __restrict__ bias,
                       unsigned short* __restrict__ Gb,
                       unsigned short* __restrict__ UbT,
                       const float* __restrict__ filt,
                       float* __restrict__ filtT) {
    __shared__ __align__(16) char gsm[49152];
    unsigned short (*As)[4096] = (unsigned short(*)[4096])(gsm);
    unsigned short (*B1)[4096] = (unsigned short(*)[4096])(gsm + 16384);
    unsigned short (*B2)[4096] = (unsigned short(*)[4096])(gsm + 32768);
    const int tid = threadIdx.x;
    const int wid = tid >> 6, lane = tid & 63;
    const int bid = blockIdx.y * 4 + blockIdx.x;

    if (bid >= 2048) {                       // ---- filt transpose (1024 blocks)
        float (*tile)[65] = (float(*)[65])gsm;
        const int li = bid - 2048;
        const int c0 = (li & 7) * 64, r0 = (li >> 3) * 64;
        const int rr = tid >> 4, c4 = (tid & 15) * 4;
        #pragma unroll
        for (int p = 0; p < 4; ++p) {
            const int r = rr + p*16;
            float4 v = *(const float4*)&filt[(size_t)(r0 + r)*DIM + c0 + c4];
            tile[r][c4+0]=v.x; tile[r][c4+1]=v.y; tile[r][c4+2]=v.z; tile[r][c4+3]=v.w;
        }
        __syncthreads();
        const int cc = tid >> 4, r4 = (tid & 15) * 4;
        #pragma unroll
        for (int p = 0; p < 4; ++p) {
            const int c = cc + p*16;
            float4 o = make_float4(tile[r4+0][c], tile[r4+1][c], tile[r4+2][c], tile[r4+3][c]);
            *(float4*)&filtT[(size_t)(c0 + c)*NS + r0 + r4] = o;
        }
        return;
    }

    const bool is_u = bid >= 1024;
    const int lbid = bid & 1023;
    const int swz = (lbid & 7) * 128 + (lbid >> 3);
    const int m0 = (swz >> 2) * 128, n0 = (swz & 3) * 128;
    const int srow = wid*16 + (lane >> 2);
    const int scol = (lane & 3) * 8;
    const unsigned short* gA = A + (size_t)(m0 + srow)*DIM + scol;
    const int wr = wid >> 1, wc = wid & 1;
    const int fr = lane & 15, fq = lane >> 4;

    if (!is_u) {
        const unsigned short* gBv = BT + (size_t)(n0 + srow)*DIM + scol;
        const unsigned short* gBz = BT + (size_t)(1024 + n0 + srow)*DIM + scol;
        f32x4 accv[4][4] = {};
        f32x4 accz[4][4] = {};
        gload16(gA,                   &As[0][wid*512]);
        gload16(gA  + (size_t)64*DIM, &As[0][wid*512 + 2048]);
        gload16(gBv,                  &B1[0][wid*512]);
        gload16(gBv + (size_t)64*DIM, &B1[0][wid*512 + 2048]);
        gload16(gBz,                  &B2[0][wid*512]);
        gload16(gBz + (size_t)64*DIM, &B2[0][wid*512 + 2048]);
        int cur = 0;
        for (int k0 = 0; k0 < DIM; k0 += 32) {
            __syncthreads();
            if (k0 + 32 < DIM) {
                const int nx = cur ^ 1;
                gload16(gA  + k0 + 32,                  &As[nx][wid*512]);
                gload16(gA  + k0 + 32 + (size_t)64*DIM, &As[nx][wid*512 + 2048]);
                gload16(gBv + k0 + 32,                  &B1[nx][wid*512]);
                gload16(gBv + k0 + 32 + (size_t)64*DIM, &B1[nx][wid*512 + 2048]);
                gload16(gBz + k0 + 32,                  &B2[nx][wid*512]);
                gload16(gBz + k0 + 32 + (size_t)64*DIM, &B2[nx][wid*512 + 2048]);
            }
            bf16x8 af[4], bf_[4];
            #pragma unroll
            for (int mi = 0; mi < 4; ++mi)
                af[mi] = *(const bf16x8*)&As[cur][(wr*64 + mi*16 + fr)*32 + fq*8];
            #pragma unroll
            for (int ni = 0; ni < 4; ++ni)
                bf_[ni] = *(const bf16x8*)&B1[cur][(wc*64 + ni*16 + fr)*32 + fq*8];
            #pragma unroll
            for (int mi = 0; mi < 4; ++mi)
                #pragma unroll
                for (int ni = 0; ni < 4; ++ni)
                    accv[mi][ni] = __builtin_amdgcn_mfma_f32_16x16x32_bf16(af[mi], bf_[ni], accv[mi][ni], 0, 0, 0);
            #pragma unroll
            for (int ni = 0; ni < 4; ++ni)
                bf_[ni] = *(const bf16x8*)&B2[cur][(wc*64 + ni*16 + fr)*32 + fq*8];
            #pragma unroll
            for (int mi = 0; mi < 4; ++mi)
                #pragma unroll
                for (int ni = 0; ni < 4; ++ni)
                    accz[mi][ni] = __builtin_amdgcn_mfma_f32_16x16x32_bf16(af[mi], bf_[ni], accz[mi][ni], 0, 0, 0);
            cur ^= 1;
        }
        #pragma unroll
        for (int ni = 0; ni < 4; ++ni) {
            const int c = n0 + wc*64 + ni*16 + fr;
            const float bv = bias[c];
            const float bz = bias[1024 + c];
            #pragma unroll
            for (int mi = 0; mi < 4; ++mi) {
                const int rbase = m0 + wr*64 + mi*16 + fq*4;
                #pragma unroll
                for (int j = 0; j < 4; ++j) {
                    const size_t idx = (size_t)(rbase + j)*DIM + c;
                    const float vv = accv[mi][ni][j] + bv;
                    const float zz = accz[mi][ni][j] + bz;
                    const float sg = 1.0f / (1.0f + __expf(-zz));
                    Gb[idx] = f2bf(vv * sg);
                }
            }
        }
    } else {
        const unsigned short* gBu = BT + (size_t)(512 + n0 + srow)*DIM + scol;
        f32x4 acc[4][4] = {};
        gload16(gA,                   &As[0][wid*512]);
        gload16(gA  + (size_t)64*DIM, &As[0][wid*512 + 2048]);
        gload16(gBu,                  &B1[0][wid*512]);
        gload16(gBu + (size_t)64*DIM, &B1[0][wid*512 + 2048]);
        int cur = 0;
        for (int k0 = 0; k0 < DIM; k0 += 32) {
            __syncthreads();
            if (k0 + 32 < DIM) {
                const int nx = cur ^ 1;
                gload16(gA  + k0 + 32,                  &As[nx][wid*512]);
                gload16(gA  + k0 + 32 + (size_t)64*DIM, &As[nx][wid*512 + 2048]);
                gload16(gBu + k0 + 32,                  &B1[nx][wid*512]);
                gload16(gBu + k0 + 32 + (size_t)64*DIM, &B1[nx][wid*512 + 2048]);
            }
            bf16x8 af[4], bf_[4];
            #pragma unroll
            for (int mi = 0; mi < 4; ++mi)
                af[mi] = *(const bf16x8*)&As[cur][(wr*64 + mi*16 + fr)*32 + fq*8];
            #pragma unroll
            for (int ni = 0; ni < 4; ++ni)
                bf_[ni] = *(const bf16x8*)&B1[cur][(wc*64 + ni*16 + fr)*32 + fq*8];
            #pragma unroll
            for (int mi = 0; mi < 4; ++mi)
                #pragma unroll
                for (int ni = 0; ni < 4; ++ni)
                    acc[mi][ni] = __builtin_amdgcn_mfma_f32_16x16x32_bf16(af[mi], bf_[ni], acc[mi][ni], 0, 0, 0);
            cur ^= 1;
        }
        // ---- epilogue: transpose 128(s) x 128(d) tile in LDS, write u^T (B,D,S)
        __syncthreads();                     // staging LDS reads complete
        unsigned short (*tileT)[136] = (unsigned short(*)[136])gsm;   // 34.8 KB < 48 KB
        #pragma unroll
        for (int ni = 0; ni < 4; ++ni) {
            const int dl = wc*64 + ni*16 + fr;
            const float bu = bias[512 + n0 + dl];
            #pragma unroll
            for (int mi = 0; mi < 4; ++mi) {
                const int slb = wr*64 + mi*16 + fq*4;
                #pragma unroll
                for (int j = 0; j < 4; ++j)
                    tileT[dl][slb + j] = f2bf(acc[mi][ni][j] + bu);
            }
        }
        __syncthreads();
        const int b   = m0 >> 13;
        const int s0m = m0 & (NS - 1);
        const int row  = tid >> 1;
        const int half = (tid & 1) * 64;
        unsigned short* dst = UbT + ((size_t)(b*DIM + n0 + row))*NS + s0m + half;
        const unsigned short* srcT = &tileT[row][half];
        #pragma unroll
        for (int i = 0; i < 8; ++i)
            *(short8v*)(dst + i*8) = *(const short8v*)(srcT + i*8);
    }
}

// ---------------------------------------------------------------- launcher
extern "C" void kernel_launch(void* const* d_in, const int* in_sizes, int n_in,
                              void* d_out, int out_size, void* d_ws, size_t ws_size,
                              hipStream_t stream) {
    const float* x      = (const float*)d_in[0];
    const float* w1     = (const float*)d_in[1];
    const float* b1     = (const float*)d_in[2];
    const float* w2     = (const float*)d_in[3];
    const float* b2     = (const float*)d_in[4];
    const float* w3     = (const float*)d_in[5];
    const float* b3     = (const float*)d_in[6];
    const float* conv_w = (const float*)d_in[7];
    const float* conv_b = (const float*)d_in[8];
    const float* w_in   = (const float*)d_in[9];
    const float* b_in   = (const float*)d_in[10];
    const float* w_out  = (const float*)d_in[11];
    const float* b_out  = (const float*)d_in[12];
    float* out = (float*)d_out;

    const size_t NEED = 167772160ULL;              // 160 MiB (known to fit)
    if (ws_size < NEED) return;
    char* ws = (char*)d_ws;
    float2*         Fbr    = (float2*)ws;                               // [0,32M)
    float*          filt   = (float*)ws;                                // [0,16M) temp
    unsigned short* xb     = (unsigned short*)(ws + (size_t)( 32<<20)); // [32,64M)
    unsigned short* W2     = (unsigned short*)(ws + (size_t)( 64<<20)); // [64,96M) g0/g
    unsigned short* W3     = (unsigned short*)(ws + (size_t)( 96<<20)); // [96,128M) u^T (B,D,S)
    char*           W4     = ws + (size_t)(128<<20);
    unsigned short* w_inT  = (unsigned short*)W4;
    unsigned short* w_outT = (unsigned short*)(W4 + (size_t)(2<<20));
    float*          filtT  = (float*)(W4 + (size_t)(4<<20));            // 16 MiB private

    // 1. mega prep: cast x, cast+T weights, filter MLP -> filt (S,D)@[0,16M)
    mega_prep_kernel<<<10496, 256, 0, stream>>>(x, xb, w_in, w_inT, w_out, w_outT,
                                                w1, b1, w2, b2, w3, b3, filt);
    // 2. merged: g0 -> W2, u^T -> W3 (transposed epilogue), filt -> filtT
    gemm_vzu2t_kernel<<<dim3(4, 768), 256, 0, stream>>>(xb, w_inT, b_in, W2, W3, filt, filtT);
    // 3. filter spectrum filtT -> Fbr (overwrites filt; already consumed)
    fft_filt_kernel<<<DIM, FT, 0, stream>>>(filtT, Fbr);
    // 4. inline depthwise conv + packed FFT circular conv, in-place on W3 rows
    fft_conv_kernel<<<(NB/2)*DIM, FT, 0, stream>>>(W3, Fbr, conv_w, conv_b);
    // 5. g = g0 * y (transposed read of W3), in-place on W2
    gate_kernel<<<NB*(NS/64)*(DIM/64), 256, 0, stream>>>(W2, W3);
    // 6. out = g @ w_out + b_out -> d_out fp32
    gemm_bt_kernel<2><<<dim3(4, MTOT/128), 256, 0, stream>>>(W2, w_outT, b_out, out, nullptr);
}

// Round 18
// 244.142 us; speedup vs baseline: 1.7727x; 1.0119x over previous
//
#include <hip/hip_runtime.h>
#include <math.h>

#define DIM   512
#define NB    4
#define NS    8192
#define FFT_N 8192
#define FT    1024
#define MTOT  (NB*NS)

// padded LDS index map for FFT stages
#define IDX(i) ((i) + ((i) >> 3))
#define XSZ   9216

typedef __attribute__((ext_vector_type(8))) short bf16x8;
typedef __attribute__((ext_vector_type(4))) short short4v;
typedef __attribute__((ext_vector_type(8))) short short8v;
typedef __attribute__((ext_vector_type(4))) float f32x4;

// ---------------------------------------------------------------- helpers
__device__ __forceinline__ float bf2f(unsigned short u) {
    union { unsigned int i; float f; } v; v.i = ((unsigned int)u) << 16; return v.f;
}
__device__ __forceinline__ unsigned short f2bf(float f) {
    union { float f; unsigned int i; } v; v.f = f;
    unsigned int r = v.i + 0x7fffu + ((v.i >> 16) & 1u);
    return (unsigned short)(r >> 16);
}
__device__ __forceinline__ float2 cmulf(float2 a, float2 b) {
    return make_float2(a.x*b.x - a.y*b.y, a.x*b.y + a.y*b.x);
}
__device__ __forceinline__ float2 cadd(float2 a, float2 b) { return make_float2(a.x+b.x, a.y+b.y); }
__device__ __forceinline__ float2 csub(float2 a, float2 b) { return make_float2(a.x-b.x, a.y-b.y); }
__device__ __forceinline__ float gelu_exact(float x) {
    return 0.5f * x * (1.0f + erff(x * 0.70710678118654752f));
}
__device__ __forceinline__ void gload16(const void* g, void* l) {
    __builtin_amdgcn_global_load_lds((const __attribute__((address_space(1))) void*)g,
                                     (__attribute__((address_space(3))) void*)l, 16, 0, 0);
}

// ---------------- mega prep: cast_x | castT(w_in) | castT(w_out) | filter MLP
__device__ __forceinline__ void castT_body(const float* __restrict__ in,
                                           unsigned short* __restrict__ outT,
                                           int R, int C, int bx, int by, int t,
                                           float tile[64][65]) {
    const int c0 = bx * 64, r0 = by * 64;
    const int rr = t >> 4, c4 = (t & 15) * 4;
    #pragma unroll
    for (int p = 0; p < 4; ++p) {
        const int r = rr + p*16;
        float4 v = *(const float4*)&in[(size_t)(r0 + r)*C + c0 + c4];
        tile[r][c4+0]=v.x; tile[r][c4+1]=v.y; tile[r][c4+2]=v.z; tile[r][c4+3]=v.w;
    }
    __syncthreads();
    const int cc = t >> 4, r4 = (t & 15) * 4;
    #pragma unroll
    for (int p = 0; p < 4; ++p) {
        const int c = cc + p*16;
        short4v o;
        o[0] = (short)f2bf(tile[r4+0][c]); o[1] = (short)f2bf(tile[r4+1][c]);
        o[2] = (short)f2bf(tile[r4+2][c]); o[3] = (short)f2bf(tile[r4+3][c]);
        *(short4v*)&outT[(size_t)(c0 + c)*R + r0 + r4] = o;
    }
}

__global__ void mega_prep_kernel(const float* __restrict__ x, unsigned short* __restrict__ xb,
                                 const float* __restrict__ w_in, unsigned short* __restrict__ w_inT,
                                 const float* __restrict__ w_out, unsigned short* __restrict__ w_outT,
                                 const float* __restrict__ w1, const float* __restrict__ b1,
                                 const float* __restrict__ w2, const float* __restrict__ b2,
                                 const float* __restrict__ w3, const float* __restrict__ b3,
                                 float* __restrict__ filt) {
    __shared__ float tile[64][65];
    __shared__ float h1s[4][64];
    __shared__ float h2s[4][64];
    const int bid = blockIdx.x;
    const int t = threadIdx.x;
    if (bid < 8192) {
        const size_t i = ((size_t)bid * 256 + t) * 8;
        float4 a = *(const float4*)&x[i];
        float4 b = *(const float4*)&x[i+4];
        short8v o;
        o[0]=(short)f2bf(a.x); o[1]=(short)f2bf(a.y); o[2]=(short)f2bf(a.z); o[3]=(short)f2bf(a.w);
        o[4]=(short)f2bf(b.x); o[5]=(short)f2bf(b.y); o[6]=(short)f2bf(b.z); o[7]=(short)f2bf(b.w);
        *(short8v*)&xb[i] = o;
    } else if (bid < 8384) {
        const int li = bid - 8192;
        castT_body(w_in, w_inT, DIM, 1536, li % 24, li / 24, t, tile);
    } else if (bid < 8448) {
        const int li = bid - 8384;
        castT_body(w_out, w_outT, DIM, DIM, li % 8, li / 8, t, tile);
    } else {
        const int sub = t >> 6, lane = t & 63;
        const int s = (bid - 8448) * 4 + sub;
        const float pos = (float)s / (float)(NS - 1);
        h1s[sub][lane] = gelu_exact(pos * w1[lane] + b1[lane]);
        __syncthreads();
        float acc = b2[lane];
        #pragma unroll 8
        for (int j = 0; j < 64; ++j) acc += h1s[sub][j] * w2[j*64 + lane];
        h2s[sub][lane] = gelu_exact(acc);
        __syncthreads();
        for (int d = lane; d < DIM; d += 64) {
            float o = b3[d];
            #pragma unroll 8
            for (int j = 0; j < 64; ++j) o += h2s[sub][j] * w3[j*DIM + d];
            filt[(size_t)s*DIM + d] = o;
        }
    }
}

// ---------------------------------------------------------------- FFT pieces
template<int LOGQ>
__device__ __forceinline__ void dif4_stage(float2* X) {
    const int q = 1 << LOGQ;
    const float step = -6.28318530717958647692f / (float)(4*q);
    #pragma unroll
    for (int it = 0; it < (FFT_N/4)/FT; ++it) {
        const int idx = threadIdx.x + it*FT;
        const int g = idx >> LOGQ, k = idx & (q-1);
        const int base = (g << (LOGQ+2)) + k;
        const int i0 = IDX(base), i1 = IDX(base+q), i2 = IDX(base+2*q), i3 = IDX(base+3*q);
        float2 a=X[i0], b=X[i1], c=X[i2], d=X[i3];
        float2 t0=cadd(a,c), t1=csub(a,c), t2=cadd(b,d), t3=csub(b,d);
        float2 y0=cadd(t0,t2), y2=csub(t0,t2);
        float2 y1=make_float2(t1.x+t3.y, t1.y-t3.x);
        float2 y3=make_float2(t1.x-t3.y, t1.y+t3.x);
        float sv, cv; __sincosf(step*(float)k, &sv, &cv);
        float2 w1=make_float2(cv, sv);
        float2 w2=cmulf(w1, w1);
        float2 w3=cmulf(w2, w1);
        X[i0] = y0;
        X[i1] = cmulf(y1, w1);
        X[i2] = cmulf(y2, w2);
        X[i3] = cmulf(y3, w3);
    }
    __syncthreads();
}

template<int LOGQ>
__device__ __forceinline__ void dit4_stage_inv(float2* X) {
    const int q = 1 << LOGQ;
    const float step = 6.28318530717958647692f / (float)(4*q);
    #pragma unroll
    for (int it = 0; it < (FFT_N/4)/FT; ++it) {
        const int idx = threadIdx.x + it*FT;
        const int g = idx >> LOGQ, k = idx & (q-1);
        const int base = (g << (LOGQ+2)) + k;
        const int i0 = IDX(base), i1 = IDX(base+q), i2 = IDX(base+2*q), i3 = IDX(base+3*q);
        float sv, cv; __sincosf(step*(float)k, &sv, &cv);
        float2 w1=make_float2(cv, sv);
        float2 w2=cmulf(w1, w1);
        float2 w3=cmulf(w2, w1);
        float2 u0=X[i0];
        float2 u1=cmulf(X[i1], w1);
        float2 u2=cmulf(X[i2], w2);
        float2 u3=cmulf(X[i3], w3);
        float2 s02=cadd(u0,u2), d02=csub(u0,u2);
        float2 s13=cadd(u1,u3), d13=csub(u1,u3);
        X[i0] = cadd(s02, s13);
        X[i2] = csub(s02, s13);
        X[i1] = make_float2(d02.x - d13.y, d02.y + d13.x);
        X[i3] = make_float2(d02.x + d13.y, d02.y - d13.x);
    }
    __syncthreads();
}

__device__ __forceinline__ void reg_fwd(float2* E) {
    const float C = 0.70710678118654752f;
    {
        float2 t0=cadd(E[0],E[4]), t1=csub(E[0],E[4]);
        float2 t2=cadd(E[2],E[6]), t3=csub(E[2],E[6]);
        E[0]=cadd(t0,t2);
        E[4]=csub(t0,t2);
        E[2]=make_float2(t1.x+t3.y, t1.y-t3.x);
        E[6]=make_float2(t1.x-t3.y, t1.y+t3.x);
    }
    {
        float2 t0=cadd(E[1],E[5]), t1=csub(E[1],E[5]);
        float2 t2=cadd(E[3],E[7]), t3=csub(E[3],E[7]);
        float2 y0=cadd(t0,t2), y2=csub(t0,t2);
        float2 y1=make_float2(t1.x+t3.y, t1.y-t3.x);
        float2 y3=make_float2(t1.x-t3.y, t1.y+t3.x);
        E[1]=y0;
        E[3]=make_float2(C*(y1.x+y1.y),  C*(y1.y-y1.x));
        E[5]=make_float2(y2.y, -y2.x);
        E[7]=make_float2(C*(y3.y-y3.x), -C*(y3.x+y3.y));
    }
    #pragma unroll
    for (int j = 0; j < 8; j += 2) {
        float2 a=E[j], b=E[j+1];
        E[j]=cadd(a,b); E[j+1]=csub(a,b);
    }
}
__device__ __forceinline__ void reg_inv(float2* E) {
    const float C = 0.70710678118654752f;
    #pragma unroll
    for (int j = 0; j < 8; j += 2) {
        float2 a=E[j], b=E[j+1];
        E[j]=cadd(a,b); E[j+1]=csub(a,b);
    }
    {
        float2 u0=E[0], u1=E[2], u2=E[4], u3=E[6];
        float2 s02=cadd(u0,u2), d02=csub(u0,u2);
        float2 s13=cadd(u1,u3), d13=csub(u1,u3);
        E[0]=cadd(s02,s13);
        E[4]=csub(s02,s13);
        E[2]=make_float2(d02.x - d13.y, d02.y + d13.x);
        E[6]=make_float2(d02.x + d13.y, d02.y - d13.x);
    }
    {
        float2 z1=E[3], z2=E[5], z3=E[7];
        float2 u0=E[1];
        float2 u1=make_float2(C*(z1.x - z1.y), C*(z1.x + z1.y));
        float2 u2=make_float2(-z2.y, z2.x);
        float2 u3=make_float2(-C*(z3.x + z3.y), C*(z3.x - z3.y));
        float2 s02=cadd(u0,u2), d02=csub(u0,u2);
        float2 s13=cadd(u1,u3), d13=csub(u1,u3);
        E[1]=cadd(s02,s13);
        E[5]=csub(s02,s13);
        E[3]=make_float2(d02.x - d13.y, d02.y + d13.x);
        E[7]=make_float2(d02.x + d13.y, d02.y - d13.x);
    }
}

__device__ __forceinline__ void load8p(const float2* X, int t, float2* E) {
    const float2* b = X + 9*t;
    #pragma unroll
    for (int j = 0; j < 8; ++j) E[j] = b[j];
}
__device__ __forceinline__ void store8p(float2* X, int t, const float2* E) {
    float2* b = X + 9*t;
    #pragma unroll
    for (int j = 0; j < 8; ++j) b[j] = E[j];
}

// ---------------------------------------- filter spectrum (permuted order)
__global__ __launch_bounds__(FT)
void fft_filt_kernel(const float* __restrict__ filtT, float2* __restrict__ Fbr) {
    __shared__ float2 X[XSZ];
    const int dd = blockIdx.x;
    const int t = threadIdx.x;
    const float* f = filtT + (size_t)dd * FFT_N;
    {
        float4 a = *(const float4*)(f + 8*t);
        float4 b = *(const float4*)(f + 8*t + 4);
        float2 E[8];
        E[0]=make_float2(a.x,0.f); E[1]=make_float2(a.y,0.f);
        E[2]=make_float2(a.z,0.f); E[3]=make_float2(a.w,0.f);
        E[4]=make_float2(b.x,0.f); E[5]=make_float2(b.y,0.f);
        E[6]=make_float2(b.z,0.f); E[7]=make_float2(b.w,0.f);
        store8p(X, t, E);
    }
    __syncthreads();
    dif4_stage<11>(X);
    dif4_stage<9>(X);
    dif4_stage<7>(X);
    dif4_stage<5>(X);
    dif4_stage<3>(X);
    {
        float2 E[8];
        load8p(X, t, E);
        reg_fwd(E);
        float2* o = Fbr + (size_t)dd*FFT_N + 8*t;
        #pragma unroll
        for (int j = 0; j < 8; ++j) o[j] = E[j];
    }
}

// -------- packed-pair conv+FFT, XCD-pair swizzle: partner blocks (p=0/1, same d)
// differ by bid 8 -> same XCD -> second Fbr[d] read hits L2.
__global__ __launch_bounds__(FT)
void fft_conv_kernel(unsigned short* __restrict__ uT, const float2* __restrict__ Fbr,
                     const float* __restrict__ conv_w, const float* __restrict__ conv_b) {
    __shared__ float2 X[XSZ];
    const int bid = blockIdx.x;
    const int d = (bid >> 4) * 8 + (bid & 7);
    const int p = (bid >> 3) & 1;
    unsigned short* u1 = uT + (size_t)((2*p    )*DIM + d) * FFT_N;
    unsigned short* u2 = uT + (size_t)((2*p + 1)*DIM + d) * FFT_N;
    const int t = threadIdx.x;
    {
        short8v a = *(const short8v*)(u1 + 8*t);
        short8v b = *(const short8v*)(u2 + 8*t);
        const float al = (t == 0)    ? 0.f : bf2f(u1[8*t - 1]);
        const float ar = (t == FT-1) ? 0.f : bf2f(u1[8*t + 8]);
        const float bl = (t == 0)    ? 0.f : bf2f(u2[8*t - 1]);
        const float br = (t == FT-1) ? 0.f : bf2f(u2[8*t + 8]);
        const float w0 = conv_w[d*3], w1 = conv_w[d*3+1], w2c = conv_w[d*3+2];
        const float cb = conv_b[d];
        float xa[10], xb[10];
        xa[0] = al; xb[0] = bl;
        #pragma unroll
        for (int j = 0; j < 8; ++j) {
            xa[j+1] = bf2f((unsigned short)a[j]);
            xb[j+1] = bf2f((unsigned short)b[j]);
        }
        xa[9] = ar; xb[9] = br;
        float2 E[8];
        #pragma unroll
        for (int j = 0; j < 8; ++j)
            E[j] = make_float2(w0*xa[j] + w1*xa[j+1] + w2c*xa[j+2] + cb,
                               w0*xb[j] + w1*xb[j+1] + w2c*xb[j+2] + cb);
        store8p(X, t, E);
    }
    __syncthreads();
    dif4_stage<11>(X);
    dif4_stage<9>(X);
    dif4_stage<7>(X);
    dif4_stage<5>(X);
    dif4_stage<3>(X);
    {
        float2 E[8];
        load8p(X, t, E);
        reg_fwd(E);
        const float2* F = Fbr + (size_t)d*FFT_N + 8*t;
        #pragma unroll
        for (int j = 0; j < 8; ++j) E[j] = cmulf(E[j], F[j]);
        reg_inv(E);
        store8p(X, t, E);
    }
    __syncthreads();
    dit4_stage_inv<3>(X);
    dit4_stage_inv<5>(X);
    dit4_stage_inv<7>(X);
    dit4_stage_inv<9>(X);
    dit4_stage_inv<11>(X);
    {
        float2 E[8];
        load8p(X, t, E);
        const float sc = 1.0f / (float)FFT_N;
        short8v a, b;
        #pragma unroll
        for (int j = 0; j < 8; ++j) {
            a[j] = (short)f2bf(E[j].x * sc);
            b[j] = (short)f2bf(E[j].y * sc);
        }
        *(short8v*)(u1 + 8*t) = a;
        *(short8v*)(u2 + 8*t) = b;
    }
}

// ---------------------------------------------------------------- gating
__global__ void gate_kernel(unsigned short* __restrict__ vg, const unsigned short* __restrict__ yT) {
    __shared__ float tile[64][65];
    const int bid = blockIdx.x;
    const int dt = bid & 7, st = (bid >> 3) & 127, b = bid >> 10;
    const int d0 = dt*64, s0 = st*64;
    const int t = threadIdx.x;
    const int dl = t >> 4, s4 = (t & 15) * 4;
    #pragma unroll
    for (int p = 0; p < 4; ++p) {
        const int d = dl + p*16;
        short4v y = *(const short4v*)&yT[((size_t)(b*DIM + d0 + d))*FFT_N + s0 + s4];
        tile[d][s4]  =bf2f((unsigned short)y[0]); tile[d][s4+1]=bf2f((unsigned short)y[1]);
        tile[d][s4+2]=bf2f((unsigned short)y[2]); tile[d][s4+3]=bf2f((unsigned short)y[3]);
    }
    __syncthreads();
    const int sl = t >> 4, d4 = (t & 15) * 4;
    #pragma unroll
    for (int p = 0; p < 4; ++p) {
        const int s = s0 + sl + p*16;
        unsigned short* pv = &vg[((size_t)(b*NS + s))*DIM + d0 + d4];
        short4v v = *(short4v*)pv;
        short4v o;
        #pragma unroll
        for (int j = 0; j < 4; ++j)
            o[j] = (short)f2bf(bf2f((unsigned short)v[j]) * tile[d4+j][sl + p*16]);
        *(short4v*)pv = o;
    }
}

// ---------------------------------------------------------------- bf16 GEMM
template<int MODE>
__global__ __launch_bounds__(256)
void gemm_bt_kernel(const unsigned short* __restrict__ A,
                    const unsigned short* __restrict__ BT,
                    const float* __restrict__ bias,
                    float* __restrict__ Cf,
                    unsigned short* __restrict__ Cb) {
    __shared__ unsigned short As[2][4096];
    __shared__ unsigned short Bs[2][4096];
    const int tid = threadIdx.x;
    const int wid = tid >> 6, lane = tid & 63;
    const int bid = blockIdx.y * 4 + blockIdx.x;
    const int swz = (bid & 7) * 128 + (bid >> 3);
    const int m0 = (swz >> 2) * 128, n0 = (swz & 3) * 128;
    const int srow = wid*16 + (lane >> 2);
    const int scol = (lane & 3) * 8;
    const unsigned short* gA = A  + (size_t)(m0 + srow)*DIM + scol;
    const unsigned short* gB = BT + (size_t)(n0 + srow)*DIM + scol;
    const int wr = wid >> 1, wc = wid & 1;
    const int fr = lane & 15, fq = lane >> 4;
    f32x4 acc[4][4] = {};
    gload16(gA,                  &As[0][wid*512]);
    gload16(gA + (size_t)64*DIM, &As[0][wid*512 + 2048]);
    gload16(gB,                  &Bs[0][wid*512]);
    gload16(gB + (size_t)64*DIM, &Bs[0][wid*512 + 2048]);
    int cur = 0;
    for (int k0 = 0; k0 < DIM; k0 += 32) {
        __syncthreads();
        if (k0 + 32 < DIM) {
            const int nx = cur ^ 1;
            gload16(gA + k0 + 32,                  &As[nx][wid*512]);
            gload16(gA + k0 + 32 + (size_t)64*DIM, &As[nx][wid*512 + 2048]);
            gload16(gB + k0 + 32,                  &Bs[nx][wid*512]);
            gload16(gB + k0 + 32 + (size_t)64*DIM, &Bs[nx][wid*512 + 2048]);
        }
        bf16x8 af[4], bfr[4];
        #pragma unroll
        for (int mi = 0; mi < 4; ++mi)
            af[mi] = *(const bf16x8*)&As[cur][(wr*64 + mi*16 + fr)*32 + fq*8];
        #pragma unroll
        for (int ni = 0; ni < 4; ++ni)
            bfr[ni] = *(const bf16x8*)&Bs[cur][(wc*64 + ni*16 + fr)*32 + fq*8];
        #pragma unroll
        for (int mi = 0; mi < 4; ++mi)
            #pragma unroll
            for (int ni = 0; ni < 4; ++ni)
                acc[mi][ni] = __builtin_amdgcn_mfma_f32_16x16x32_bf16(af[mi], bfr[ni], acc[mi][ni], 0, 0, 0);
        cur ^= 1;
    }
    #pragma unroll
    for (int ni = 0; ni < 4; ++ni) {
        const int c = n0 + wc*64 + ni*16 + fr;
        const float bv = bias[c];
        #pragma unroll
        for (int mi = 0; mi < 4; ++mi) {
            const int rbase = m0 + wr*64 + mi*16 + fq*4;
            #pragma unroll
            for (int j = 0; j < 4; ++j) {
                const size_t idx = (size_t)(rbase + j)*DIM + c;
                const float val = acc[mi][ni][j] + bv;
                if (MODE == 0) Cb[idx] = f2bf(val);
                else           Cf[idx] = val;
            }
        }
    }
}

// ------- merged dispatch, grid dim3(4, 768):
//   [0,1024)    g0 = (v+bv)*sigmoid(z+bz) -> Gb (B,S,D)
//   [1024,2048) u = x@Wu+bu -> UbT (B,D,S) via epilogue LDS transpose
//   [2048,3072) transpose filt (NS,DIM) -> filtT (DIM,NS)
__global__ __launch_bounds__(256)
void gemm_vzu2t_kernel(const unsigned short* __restrict__ A,
                       const unsigned short* __restrict__ BT,
                       const float* __restrict__ bias,
                       unsigned short* __restrict__ Gb,
                       unsigned short* __restrict__ UbT,
                       const float* __restrict__ filt,
                       float* __restrict__ filtT) {
    __shared__ __align__(16) char gsm[49152];
    unsigned short (*As)[4096] = (unsigned short(*)[4096])(gsm);
    unsigned short (*B1)[4096] = (unsigned short(*)[4096])(gsm + 16384);
    unsigned short (*B2)[4096] = (unsigned short(*)[4096])(gsm + 32768);
    const int tid = threadIdx.x;
    const int wid = tid >> 6, lane = tid & 63;
    const int bid = blockIdx.y * 4 + blockIdx.x;

    if (bid >= 2048) {
        float (*tile)[65] = (float(*)[65])gsm;
        const int li = bid - 2048;
        const int c0 = (li & 7) * 64, r0 = (li >> 3) * 64;
        const int rr = tid >> 4, c4 = (tid & 15) * 4;
        #pragma unroll
        for (int p = 0; p < 4; ++p) {
            const int r = rr + p*16;
            float4 v = *(const float4*)&filt[(size_t)(r0 + r)*DIM + c0 + c4];
            tile[r][c4+0]=v.x; tile[r][c4+1]=v.y; tile[r][c4+2]=v.z; tile[r][c4+3]=v.w;
        }
        __syncthreads();
        const int cc = tid >> 4, r4 = (tid & 15) * 4;
        #pragma unroll
        for (int p = 0; p < 4; ++p) {
            const int c = cc + p*16;
            float4 o = make_float4(tile[r4+0][c], tile[r4+1][c], tile[r4+2][c], tile[r4+3][c]);
            *(float4*)&filtT[(size_t)(c0 + c)*NS + r0 + r4] = o;
        }
        return;
    }

    const bool is_u = bid >= 1024;
    const int lbid = bid & 1023;
    const int swz = (lbid & 7) * 128 + (lbid >> 3);
    const int m0 = (swz >> 2) * 128, n0 = (swz & 3) * 128;
    const int srow = wid*16 + (lane >> 2);
    const int scol = (lane & 3) * 8;
    const unsigned short* gA = A + (size_t)(m0 + srow)*DIM + scol;
    const int wr = wid >> 1, wc = wid & 1;
    const int fr = lane & 15, fq = lane >> 4;

    if (!is_u) {
        const unsigned short* gBv = BT + (size_t)(n0 + srow)*DIM + scol;
        const unsigned short* gBz = BT + (size_t)(1024 + n0 + srow)*DIM + scol;
        f32x4 accv[4][4] = {};
        f32x4 accz[4][4] = {};
        gload16(gA,                   &As[0][wid*512]);
        gload16(gA  + (size_t)64*DIM, &As[0][wid*512 + 2048]);
        gload16(gBv,                  &B1[0][wid*512]);
        gload16(gBv + (size_t)64*DIM, &B1[0][wid*512 + 2048]);
        gload16(gBz,                  &B2[0][wid*512]);
        gload16(gBz + (size_t)64*DIM, &B2[0][wid*512 + 2048]);
        int cur = 0;
        for (int k0 = 0; k0 < DIM; k0 += 32) {
            __syncthreads();
            if (k0 + 32 < DIM) {
                const int nx = cur ^ 1;
                gload16(gA  + k0 + 32,                  &As[nx][wid*512]);
                gload16(gA  + k0 + 32 + (size_t)64*DIM, &As[nx][wid*512 + 2048]);
                gload16(gBv + k0 + 32,                  &B1[nx][wid*512]);
                gload16(gBv + k0 + 32 + (size_t)64*DIM, &B1[nx][wid*512 + 2048]);
                gload16(gBz + k0 + 32,                  &B2[nx][wid*512]);
                gload16(gBz + k0 + 32 + (size_t)64*DIM, &B2[nx][wid*512 + 2048]);
            }
            bf16x8 af[4], bf_[4];
            #pragma unroll
            for (int mi = 0; mi < 4; ++mi)
                af[mi] = *(const bf16x8*)&As[cur][(wr*64 + mi*16 + fr)*32 + fq*8];
            #pragma unroll
            for (int ni = 0; ni < 4; ++ni)
                bf_[ni] = *(const bf16x8*)&B1[cur][(wc*64 + ni*16 + fr)*32 + fq*8];
            #pragma unroll
            for (int mi = 0; mi < 4; ++mi)
                #pragma unroll
                for (int ni = 0; ni < 4; ++ni)
                    accv[mi][ni] = __builtin_amdgcn_mfma_f32_16x16x32_bf16(af[mi], bf_[ni], accv[mi][ni], 0, 0, 0);
            #pragma unroll
            for (int ni = 0; ni < 4; ++ni)
                bf_[ni] = *(const bf16x8*)&B2[cur][(wc*64 + ni*16 + fr)*32 + fq*8];
            #pragma unroll
            for (int mi = 0; mi < 4; ++mi)
                #pragma unroll
                for (int ni = 0; ni < 4; ++ni)
                    accz[mi][ni] = __builtin_amdgcn_mfma_f32_16x16x32_bf16(af[mi], bf_[ni], accz[mi][ni], 0, 0, 0);
            cur ^= 1;
        }
        #pragma unroll
        for (int ni = 0; ni < 4; ++ni) {
            const int c = n0 + wc*64 + ni*16 + fr;
            const float bv = bias[c];
            const float bz = bias[1024 + c];
            #pragma unroll
            for (int mi = 0; mi < 4; ++mi) {
                const int rbase = m0 + wr*64 + mi*16 + fq*4;
                #pragma unroll
                for (int j = 0; j < 4; ++j) {
                    const size_t idx = (size_t)(rbase + j)*DIM + c;
                    const float vv = accv[mi][ni][j] + bv;
                    const float zz = accz[mi][ni][j] + bz;
                    const float sg = 1.0f / (1.0f + __expf(-zz));
                    Gb[idx] = f2bf(vv * sg);
                }
            }
        }
    } else {
        const unsigned short* gBu = BT + (size_t)(512 + n0 + srow)*DIM + scol;
        f32x4 acc[4][4] = {};
        gload16(gA,                   &As[0][wid*512]);
        gload16(gA  + (size_t)64*DIM, &As[0][wid*512 + 2048]);
        gload16(gBu,                  &B1[0][wid*512]);
        gload16(gBu + (size_t)64*DIM, &B1[0][wid*512 + 2048]);
        int cur = 0;
        for (int k0 = 0; k0 < DIM; k0 += 32) {
            __syncthreads();
            if (k0 + 32 < DIM) {
                const int nx = cur ^ 1;
                gload16(gA  + k0 + 32,                  &As[nx][wid*512]);
                gload16(gA  + k0 + 32 + (size_t)64*DIM, &As[nx][wid*512 + 2048]);
                gload16(gBu + k0 + 32,                  &B1[nx][wid*512]);
                gload16(gBu + k0 + 32 + (size_t)64*DIM, &B1[nx][wid*512 + 2048]);
            }
            bf16x8 af[4], bf_[4];
            #pragma unroll
            for (int mi = 0; mi < 4; ++mi)
                af[mi] = *(const bf16x8*)&As[cur][(wr*64 + mi*16 + fr)*32 + fq*8];
            #pragma unroll
            for (int ni = 0; ni < 4; ++ni)
                bf_[ni] = *(const bf16x8*)&B1[cur][(wc*64 + ni*16 + fr)*32 + fq*8];
            #pragma unroll
            for (int mi = 0; mi < 4; ++mi)
                #pragma unroll
                for (int ni = 0; ni < 4; ++ni)
                    acc[mi][ni] = __builtin_amdgcn_mfma_f32_16x16x32_bf16(af[mi], bf_[ni], acc[mi][ni], 0, 0, 0);
            cur ^= 1;
        }
        // epilogue: transpose 128(s) x 128(d) tile in LDS, write u^T (B,D,S)
        __syncthreads();
        unsigned short (*tileT)[136] = (unsigned short(*)[136])gsm;
        #pragma unroll
        for (int ni = 0; ni < 4; ++ni) {
            const int dl = wc*64 + ni*16 + fr;
            const float bu = bias[512 + n0 + dl];
            #pragma unroll
            for (int mi = 0; mi < 4; ++mi) {
                const int slb = wr*64 + mi*16 + fq*4;
                #pragma unroll
                for (int j = 0; j < 4; ++j)
                    tileT[dl][slb + j] = f2bf(acc[mi][ni][j] + bu);
            }
        }
        __syncthreads();
        const int b   = m0 >> 13;
        const int s0m = m0 & (NS - 1);
        const int row  = tid >> 1;
        const int half = (tid & 1) * 64;
        unsigned short* dst = UbT + ((size_t)(b*DIM + n0 + row))*NS + s0m + half;
        const unsigned short* srcT = &tileT[row][half];
        #pragma unroll
        for (int i = 0; i < 8; ++i)
            *(short8v*)(dst + i*8) = *(const short8v*)(srcT + i*8);
    }
}

// ---------------------------------------------------------------- launcher
extern "C" void kernel_launch(void* const* d_in, const int* in_sizes, int n_in,
                              void* d_out, int out_size, void* d_ws, size_t ws_size,
                              hipStream_t stream) {
    const float* x      = (const float*)d_in[0];
    const float* w1     = (const float*)d_in[1];
    const float* b1     = (const float*)d_in[2];
    const float* w2     = (const float*)d_in[3];
    const float* b2     = (const float*)d_in[4];
    const float* w3     = (const float*)d_in[5];
    const float* b3     = (const float*)d_in[6];
    const float* conv_w = (const float*)d_in[7];
    const float* conv_b = (const float*)d_in[8];
    const float* w_in   = (const float*)d_in[9];
    const float* b_in   = (const float*)d_in[10];
    const float* w_out  = (const float*)d_in[11];
    const float* b_out  = (const float*)d_in[12];
    float* out = (float*)d_out;

    const size_t NEED = 167772160ULL;              // 160 MiB (known to fit)
    if (ws_size < NEED) return;
    char* ws = (char*)d_ws;
    float2*         Fbr    = (float2*)ws;                               // [0,32M)
    float*          filt   = (float*)ws;                                // [0,16M) temp
    unsigned short* xb     = (unsigned short*)(ws + (size_t)( 32<<20)); // [32,64M)
    unsigned short* W2     = (unsigned short*)(ws + (size_t)( 64<<20)); // [64,96M) g0/g
    unsigned short* W3     = (unsigned short*)(ws + (size_t)( 96<<20)); // [96,128M) u^T (B,D,S)
    char*           W4     = ws + (size_t)(128<<20);
    unsigned short* w_inT  = (unsigned short*)W4;
    unsigned short* w_outT = (unsigned short*)(W4 + (size_t)(2<<20));
    float*          filtT  = (float*)(W4 + (size_t)(4<<20));            // 16 MiB private

    // 1. mega prep: cast x, cast+T weights, filter MLP -> filt (S,D)@[0,16M)
    mega_prep_kernel<<<10496, 256, 0, stream>>>(x, xb, w_in, w_inT, w_out, w_outT,
                                                w1, b1, w2, b2, w3, b3, filt);
    // 2. merged: g0 -> W2, u^T -> W3 (transposed epilogue), filt -> filtT
    gemm_vzu2t_kernel<<<dim3(4, 768), 256, 0, stream>>>(xb, w_inT, b_in, W2, W3, filt, filtT);
    // 3. filter spectrum filtT -> Fbr (overwrites filt; already consumed)
    fft_filt_kernel<<<DIM, FT, 0, stream>>>(filtT, Fbr);
    // 4. inline depthwise conv + packed FFT circular conv, in-place on W3 rows
    fft_conv_kernel<<<(NB/2)*DIM, FT, 0, stream>>>(W3, Fbr, conv_w, conv_b);
    // 5. g = g0 * y (transposed read of W3), in-place on W2
    gate_kernel<<<NB*(NS/64)*(DIM/64), 256, 0, stream>>>(W2, W3);
    // 6. out = g @ w_out + b_out -> d_out fp32
    gemm_bt_kernel<2><<<dim3(4, MTOT/128), 256, 0, stream>>>(W2, w_outT, b_out, out, nullptr);
}